// Round 3
// baseline (676.433 us; speedup 1.0000x reference)
//
#include <hip/hip_runtime.h>
#include <cmath>

// ---------------------------------------------------------------------------
// Agent-attention block, MI355X gfx950.
// qkv channel layout (reference reshape (B,NH,3KD,N)): per head nh,
//   q = channels nh*96 + [0,32), k = nh*96 + [32,64), v = nh*96 + [64,96).
// Pipeline:
//   K0a/K0b: pb[nh][g][n], ab[nh][n][g] (bilinear 7x7->64x64 + axial biases)
//   K1: qkv = BN(W @ x) -> bf16 [B][768][N]   (MFMA 16x16x32 bf16)
//   K2: agent pooling (exact reference reshape semantics) -> aT[b][nh][g][kd]
//   K3: flash stage-1: softmax_n(aT.k*scale+pb) @ v^T -> attnT[b][nh][kd][g]
//   K4: stage-2: softmax_g(q^T.a*scale+ab) @ attn -> outa [b][c][n] bf16 (c=nh*32+kd)
//   K5: outa += BN(dwconv3x3(v))  (in-place)
//   K6: out = BN(projW @ outa) -> float32 d_out
// ---------------------------------------------------------------------------

typedef __bf16 bf16;
typedef bf16 bf16x8 __attribute__((ext_vector_type(8)));
typedef float f32x4 __attribute__((ext_vector_type(4)));

__device__ __forceinline__ f32x4 MFMA16(bf16x8 a, bf16x8 b, f32x4 c) {
  return __builtin_amdgcn_mfma_f32_16x16x32_bf16(a, b, c, 0, 0, 0);
}

constexpr int B_ = 16, C_ = 256, N_ = 4096;
constexpr int NH_ = 8, KD_ = 32, AG_ = 64, O3_ = 768;
constexpr float SCALE_ = 0.17677669529663687f;  // 32^-0.5

// ------------------------------ bias kernels -------------------------------
__device__ __forceinline__ float bilerp7(const float* __restrict__ A, int h, int w) {
  float fy = (h + 0.5f) * (7.0f / 64.0f) - 0.5f;
  float fx = (w + 0.5f) * (7.0f / 64.0f) - 0.5f;
  float fy0 = floorf(fy), fx0 = floorf(fx);
  float wy = fy - fy0, wx = fx - fx0;
  int y0 = (int)fy0, x0 = (int)fx0;
  int y0c = min(max(y0, 0), 6), y1c = min(max(y0 + 1, 0), 6);
  int x0c = min(max(x0, 0), 6), x1c = min(max(x0 + 1, 0), 6);
  float a00 = A[y0c * 7 + x0c], a01 = A[y0c * 7 + x1c];
  float a10 = A[y1c * 7 + x0c], a11 = A[y1c * 7 + x1c];
  return (1.0f - wy) * ((1.0f - wx) * a00 + wx * a01) +
         wy * ((1.0f - wx) * a10 + wx * a11);
}

__global__ __launch_bounds__(256) void bias_pb_kernel(
    const float* __restrict__ an, const float* __restrict__ ah,
    const float* __restrict__ aw, float* __restrict__ pb) {
  int tid = blockIdx.x * 256 + threadIdx.x;  // nh,g,n  (n fastest)
  int n = tid & (N_ - 1);
  int g = (tid >> 12) & 63;
  int nh = tid >> 18;
  int h = n >> 6, w = n & 63;
  float v = bilerp7(an + (nh * AG_ + g) * 49, h, w);
  pb[tid] = v + ah[(nh * AG_ + g) * 64 + h] + aw[(nh * AG_ + g) * 64 + w];
}

__global__ __launch_bounds__(256) void bias_ab_kernel(
    const float* __restrict__ na, const float* __restrict__ ha,
    const float* __restrict__ wa, float* __restrict__ ab) {
  int tid = blockIdx.x * 256 + threadIdx.x;  // nh,n,g  (g fastest)
  int g = tid & 63;
  int n = (tid >> 6) & (N_ - 1);
  int nh = tid >> 18;
  int h = n >> 6, w = n & 63;
  float v = bilerp7(na + (nh * AG_ + g) * 49, h, w);
  ab[tid] = v + ha[(nh * 64 + h) * AG_ + g] + wa[(nh * 64 + w) * AG_ + g];
}

// ------------------------------ K1: qkv GEMM -------------------------------
__global__ __launch_bounds__(256) void qkv_gemm_kernel(
    const float* __restrict__ x, const float* __restrict__ w,
    const float* __restrict__ bn, bf16* __restrict__ qkv) {
  int nt = blockIdx.x * 128, ot = blockIdx.y * 128, b = blockIdx.z;
  __shared__ __align__(16) bf16 As[128][40];
  __shared__ __align__(16) bf16 Bs[128][40];
  int t = threadIdx.x, wave = t >> 6, lane = t & 63, quad = lane >> 4, l16 = lane & 15;
  int wm = (wave >> 1) * 64, wn = (wave & 1) * 64;
  f32x4 acc[4][4];
#pragma unroll
  for (int mi = 0; mi < 4; mi++)
#pragma unroll
    for (int ni = 0; ni < 4; ni++) acc[mi][ni] = (f32x4){0.f, 0.f, 0.f, 0.f};
  const float* xb = x + (size_t)b * C_ * N_;
  for (int k0 = 0; k0 < 256; k0 += 32) {
    __syncthreads();
#pragma unroll
    for (int i = 0; i < 4; i++) {  // A: W[ot..+128][k0..+32]
      int f = t + i * 256;
      int o = f >> 3, cq = (f & 7) * 4;
      float4 v4 = *(const float4*)(w + (size_t)(ot + o) * C_ + k0 + cq);
      As[o][cq] = (bf16)v4.x; As[o][cq + 1] = (bf16)v4.y;
      As[o][cq + 2] = (bf16)v4.z; As[o][cq + 3] = (bf16)v4.w;
    }
#pragma unroll
    for (int i = 0; i < 4; i++) {  // B: x[k0..+32][nt..+128] -> Bs[n][k]
      int f = t + i * 256;
      int c = f >> 5, nq = (f & 31) * 4;
      float4 v4 = *(const float4*)(xb + (size_t)(k0 + c) * N_ + nt + nq);
      Bs[nq][c] = (bf16)v4.x; Bs[nq + 1][c] = (bf16)v4.y;
      Bs[nq + 2][c] = (bf16)v4.z; Bs[nq + 3][c] = (bf16)v4.w;
    }
    __syncthreads();
    bf16x8 af[4], bfv[4];
#pragma unroll
    for (int mi = 0; mi < 4; mi++)
      af[mi] = *(const bf16x8*)&As[wm + mi * 16 + l16][quad * 8];
#pragma unroll
    for (int ni = 0; ni < 4; ni++)
      bfv[ni] = *(const bf16x8*)&Bs[wn + ni * 16 + l16][quad * 8];
#pragma unroll
    for (int mi = 0; mi < 4; mi++)
#pragma unroll
      for (int ni = 0; ni < 4; ni++)
        acc[mi][ni] = MFMA16(af[mi], bfv[ni], acc[mi][ni]);
  }
  bf16* outb = qkv + (size_t)b * O3_ * N_;
#pragma unroll
  for (int mi = 0; mi < 4; mi++) {
    int o0 = ot + wm + mi * 16 + quad * 4;
    float4 g4 = *(const float4*)(bn + 0 * O3_ + o0);
    float4 b4 = *(const float4*)(bn + 1 * O3_ + o0);
    float4 m4 = *(const float4*)(bn + 2 * O3_ + o0);
    float4 v4 = *(const float4*)(bn + 3 * O3_ + o0);
    float sc[4], sh[4];
    sc[0] = g4.x * rsqrtf(v4.x + 1e-5f); sh[0] = b4.x - m4.x * sc[0];
    sc[1] = g4.y * rsqrtf(v4.y + 1e-5f); sh[1] = b4.y - m4.y * sc[1];
    sc[2] = g4.z * rsqrtf(v4.z + 1e-5f); sh[2] = b4.z - m4.z * sc[2];
    sc[3] = g4.w * rsqrtf(v4.w + 1e-5f); sh[3] = b4.w - m4.w * sc[3];
#pragma unroll
    for (int ni = 0; ni < 4; ni++) {
      int n = nt + wn + ni * 16 + l16;
#pragma unroll
      for (int r = 0; r < 4; r++)
        outb[(size_t)(o0 + r) * N_ + n] = (bf16)(acc[mi][ni][r] * sc[r] + sh[r]);
    }
  }
}

// ------------------------------ K2: agent pooling --------------------------
// a[b][nh2][kd2][g] = (1/64) sum_{hi,wi} qkv[b][ho*96 + hi*4 + ((wo*8+wi)>>4)]
//                                           [(((wo*8+wi)&15)*4 + (c>>6))*64 + (c&63)]
// with c = nh2*32+kd2, ho=g>>3, wo=g&7.  Stored aT[b][nh][g][kd].
__global__ __launch_bounds__(256) void pool_kernel(
    const bf16* __restrict__ qkv, bf16* __restrict__ aT) {
  int tid = blockIdx.x * 256 + threadIdx.x;  // (((b*8+nh2)*64+g)*32+kd2)
  int kd2 = tid & 31;
  int g = (tid >> 5) & 63;
  int nh2 = (tid >> 11) & 7;
  int b = tid >> 14;
  int c = nh2 * KD_ + kd2;
  int ho = g >> 3, wo = g & 7;
  int ww = c & 63, ch = c >> 6;
  const bf16* qb = qkv + (size_t)b * O3_ * N_;
  float s = 0.f;
#pragma unroll
  for (int wi = 0; wi < 8; wi++) {
    int w_ = wo * 8 + wi;
    int n1 = ((w_ & 15) * 4 + ch) * 64 + ww;
    int kdb = ho * 96 + (w_ >> 4);
#pragma unroll
    for (int hi = 0; hi < 8; hi++)
      s += (float)qb[(size_t)(kdb + hi * 4) * N_ + n1];
  }
  aT[tid] = (bf16)(s * (1.0f / 64.0f));
}

// ------------------------------ K3: flash stage 1 --------------------------
struct SM3main { bf16 kT[256][40]; bf16 Ps[4][64][72]; };
struct SM3comb { float m[4][64]; float l[4][64]; float o[4][64][32]; };
union SM3u { SM3main a; SM3comb c; };

__global__ __launch_bounds__(256) void attn1_kernel(
    const bf16* __restrict__ qkv, const bf16* __restrict__ aT,
    const float* __restrict__ pb, bf16* __restrict__ attnT) {
  __shared__ __align__(16) SM3u sm;
  int bh = blockIdx.x, b = bh >> 3, nh = bh & 7;
  int t = threadIdx.x, wave = t >> 6, lane = t & 63, quad = lane >> 4, l16 = lane & 15;
  const bf16* aTb = aT + (size_t)bh * (AG_ * KD_);
  const bf16* kb = qkv + (size_t)b * O3_ * N_ + (size_t)(nh * 96 + 32) * N_;
  const bf16* vb = qkv + (size_t)b * O3_ * N_ + (size_t)(nh * 96 + 64) * N_;
  const float* pbh = pb + (size_t)nh * AG_ * N_;
  bf16x8 af[4];
#pragma unroll
  for (int mi = 0; mi < 4; mi++)
    af[mi] = *(const bf16x8*)(aTb + (mi * 16 + l16) * KD_ + quad * 8);
  float mrow[4][4], lrow[4][4];
  f32x4 oacc[4][2];
#pragma unroll
  for (int mi = 0; mi < 4; mi++)
#pragma unroll
    for (int r = 0; r < 4; r++) { mrow[mi][r] = -1e30f; lrow[mi][r] = 0.f; }
#pragma unroll
  for (int mi = 0; mi < 4; mi++) {
    oacc[mi][0] = (f32x4){0.f, 0.f, 0.f, 0.f};
    oacc[mi][1] = (f32x4){0.f, 0.f, 0.f, 0.f};
  }
  for (int it = 0; it < 16; it++) {
    int ntile = it * 256;
    __syncthreads();
#pragma unroll
    for (int i = 0; i < 4; i++) {  // stage k[32][256] -> kT[n][kd]
      int f = t + i * 256;
      int kd = f >> 5, nq = (f & 31) * 8;
      union { uint4 u; bf16 e[8]; } pk;
      pk.u = *(const uint4*)(kb + (size_t)kd * N_ + ntile + nq);
#pragma unroll
      for (int j = 0; j < 8; j++) sm.a.kT[nq + j][kd] = pk.e[j];
    }
    __syncthreads();
    int nloc = wave * 64, ng = ntile + nloc;
    bf16x8 kf[4];
#pragma unroll
    for (int ni = 0; ni < 4; ni++)
      kf[ni] = *(const bf16x8*)&sm.a.kT[nloc + ni * 16 + l16][quad * 8];
#pragma unroll
    for (int mi = 0; mi < 4; mi++) {
      f32x4 zero4 = (f32x4){0.f, 0.f, 0.f, 0.f};
      f32x4 s[4];
#pragma unroll
      for (int ni = 0; ni < 4; ni++)
        s[ni] = MFMA16(af[mi], kf[ni], zero4);
      int g0 = mi * 16 + quad * 4;
#pragma unroll
      for (int ni = 0; ni < 4; ni++) {
        const float* p = pbh + (size_t)g0 * N_ + ng + ni * 16 + l16;
#pragma unroll
        for (int r = 0; r < 4; r++) s[ni][r] = s[ni][r] * SCALE_ + p[(size_t)r * N_];
      }
#pragma unroll
      for (int r = 0; r < 4; r++) {
        float mx = fmaxf(fmaxf(s[0][r], s[1][r]), fmaxf(s[2][r], s[3][r]));
#pragma unroll
        for (int off = 1; off < 16; off <<= 1) mx = fmaxf(mx, __shfl_xor(mx, off));
        float mnew = fmaxf(mrow[mi][r], mx);
        float alpha = __expf(mrow[mi][r] - mnew);
        mrow[mi][r] = mnew;
        float rs = 0.f;
#pragma unroll
        for (int ni = 0; ni < 4; ni++) {
          float pv = __expf(s[ni][r] - mnew);
          s[ni][r] = pv; rs += pv;
        }
#pragma unroll
        for (int off = 1; off < 16; off <<= 1) rs += __shfl_xor(rs, off);
        lrow[mi][r] = lrow[mi][r] * alpha + rs;
        oacc[mi][0][r] *= alpha; oacc[mi][1][r] *= alpha;
      }
#pragma unroll
      for (int ni = 0; ni < 4; ni++)
#pragma unroll
        for (int r = 0; r < 4; r++)
          sm.a.Ps[wave][mi * 16 + quad * 4 + r][ni * 16 + l16] = (bf16)s[ni][r];
    }
#pragma unroll
    for (int ks = 0; ks < 2; ks++) {
      bf16x8 vf[2], pf[4];
#pragma unroll
      for (int ci = 0; ci < 2; ci++) {
        union { uint4 u; bf16x8 v; } pk;
        pk.u = *(const uint4*)(vb + (size_t)(ci * 16 + l16) * N_ + ng + ks * 32 + quad * 8);
        vf[ci] = pk.v;
      }
#pragma unroll
      for (int mi = 0; mi < 4; mi++)
        pf[mi] = *(const bf16x8*)&sm.a.Ps[wave][mi * 16 + l16][ks * 32 + quad * 8];
#pragma unroll
      for (int mi = 0; mi < 4; mi++)
#pragma unroll
        for (int ci = 0; ci < 2; ci++)
          oacc[mi][ci] = MFMA16(pf[mi], vf[ci], oacc[mi][ci]);
    }
  }
  __syncthreads();
#pragma unroll
  for (int mi = 0; mi < 4; mi++)
#pragma unroll
    for (int r = 0; r < 4; r++) {
      int g = mi * 16 + quad * 4 + r;
      if (l16 == 0) { sm.c.m[wave][g] = mrow[mi][r]; sm.c.l[wave][g] = lrow[mi][r]; }
      sm.c.o[wave][g][l16] = oacc[mi][0][r];
      sm.c.o[wave][g][16 + l16] = oacc[mi][1][r];
    }
  __syncthreads();
  {
    int g = t >> 2, kd0 = (t & 3) * 8;
    float M = fmaxf(fmaxf(sm.c.m[0][g], sm.c.m[1][g]), fmaxf(sm.c.m[2][g], sm.c.m[3][g]));
    float ew[4], L = 0.f;
#pragma unroll
    for (int w2 = 0; w2 < 4; w2++) {
      ew[w2] = __expf(sm.c.m[w2][g] - M);
      L += sm.c.l[w2][g] * ew[w2];
    }
    float invL = 1.0f / L;
    bf16* dst = attnT + (size_t)bh * (KD_ * AG_);
#pragma unroll
    for (int j = 0; j < 8; j++) {
      int kd = kd0 + j;
      float v = 0.f;
#pragma unroll
      for (int w2 = 0; w2 < 4; w2++) v += sm.c.o[w2][g][kd] * ew[w2];
      dst[kd * AG_ + g] = (bf16)(v * invL);
    }
  }
}

// ------------------------------ K4: stage 2 --------------------------------
struct SM4 { bf16 qT[256][40]; bf16 Ps[4][64][72]; };

__global__ __launch_bounds__(256) void attn2_kernel(
    const bf16* __restrict__ qkv, const bf16* __restrict__ aT,
    const bf16* __restrict__ attnT, const float* __restrict__ ab,
    bf16* __restrict__ outa) {
  __shared__ __align__(16) SM4 sm;
  int nt = blockIdx.x * 256;
  int bh = blockIdx.y, b = bh >> 3, nh = bh & 7;
  int t = threadIdx.x, wave = t >> 6, lane = t & 63, quad = lane >> 4, l16 = lane & 15;
  const bf16* qb = qkv + (size_t)b * O3_ * N_ + (size_t)(nh * 96) * N_;
#pragma unroll
  for (int i = 0; i < 4; i++) {  // stage q[32][256] -> qT[n][kd]
    int f = t + i * 256;
    int kd = f >> 5, nq = (f & 31) * 8;
    union { uint4 u; bf16 e[8]; } pk;
    pk.u = *(const uint4*)(qb + (size_t)kd * N_ + nt + nq);
#pragma unroll
    for (int j = 0; j < 8; j++) sm.qT[nq + j][kd] = pk.e[j];
  }
  const bf16* aTb = aT + (size_t)bh * (AG_ * KD_);
  const bf16* atb = attnT + (size_t)bh * (KD_ * AG_);
  bf16x8 afr[4], tfr[2][2];
#pragma unroll
  for (int gi = 0; gi < 4; gi++)
    afr[gi] = *(const bf16x8*)(aTb + (gi * 16 + l16) * KD_ + quad * 8);
#pragma unroll
  for (int ci = 0; ci < 2; ci++)
#pragma unroll
    for (int ks = 0; ks < 2; ks++)
      tfr[ci][ks] = *(const bf16x8*)(atb + (ci * 16 + l16) * AG_ + ks * 32 + quad * 8);
  const float* abh = ab + (size_t)nh * N_ * AG_;
  __syncthreads();
  int nloc = wave * 64;
#pragma unroll
  for (int mi = 0; mi < 4; mi++) {
    bf16x8 qf = *(const bf16x8*)&sm.qT[nloc + mi * 16 + l16][quad * 8];
    f32x4 zero4 = (f32x4){0.f, 0.f, 0.f, 0.f};
    f32x4 s[4];
#pragma unroll
    for (int gi = 0; gi < 4; gi++)
      s[gi] = MFMA16(qf, afr[gi], zero4);
    int n0 = nt + nloc + mi * 16 + quad * 4;
#pragma unroll
    for (int gi = 0; gi < 4; gi++) {
      int g = gi * 16 + l16;
#pragma unroll
      for (int r = 0; r < 4; r++)
        s[gi][r] = s[gi][r] * SCALE_ + abh[(size_t)(n0 + r) * AG_ + g];
    }
#pragma unroll
    for (int r = 0; r < 4; r++) {
      float mx = fmaxf(fmaxf(s[0][r], s[1][r]), fmaxf(s[2][r], s[3][r]));
#pragma unroll
      for (int off = 1; off < 16; off <<= 1) mx = fmaxf(mx, __shfl_xor(mx, off));
      float rs = 0.f;
#pragma unroll
      for (int gi = 0; gi < 4; gi++) {
        float p = __expf(s[gi][r] - mx);
        s[gi][r] = p; rs += p;
      }
#pragma unroll
      for (int off = 1; off < 16; off <<= 1) rs += __shfl_xor(rs, off);
      float inv = 1.0f / rs;
#pragma unroll
      for (int gi = 0; gi < 4; gi++) s[gi][r] *= inv;
    }
#pragma unroll
    for (int gi = 0; gi < 4; gi++)
#pragma unroll
      for (int r = 0; r < 4; r++)
        sm.Ps[wave][mi * 16 + quad * 4 + r][gi * 16 + l16] = (bf16)s[gi][r];
  }
  __syncthreads();
  f32x4 O[4][2];
#pragma unroll
  for (int mi = 0; mi < 4; mi++) {
    O[mi][0] = (f32x4){0.f, 0.f, 0.f, 0.f};
    O[mi][1] = (f32x4){0.f, 0.f, 0.f, 0.f};
  }
#pragma unroll
  for (int ks = 0; ks < 2; ks++) {
    bf16x8 pf[4];
#pragma unroll
    for (int mi = 0; mi < 4; mi++)
      pf[mi] = *(const bf16x8*)&sm.Ps[wave][mi * 16 + l16][ks * 32 + quad * 8];
#pragma unroll
    for (int mi = 0; mi < 4; mi++)
#pragma unroll
      for (int ci = 0; ci < 2; ci++)
        O[mi][ci] = MFMA16(pf[mi], tfr[ci][ks], O[mi][ci]);
  }
  bf16* ob = outa + (size_t)b * C_ * N_;
#pragma unroll
  for (int mi = 0; mi < 4; mi++) {
    int n0 = nt + nloc + mi * 16 + quad * 4;
#pragma unroll
    for (int ci = 0; ci < 2; ci++) {
      int c = nh * KD_ + ci * 16 + l16;
      union { ushort4 u; bf16 e[4]; } pk;
#pragma unroll
      for (int r = 0; r < 4; r++) pk.e[r] = (bf16)O[mi][ci][r];
      *(ushort4*)(ob + (size_t)c * N_ + n0) = pk.u;
    }
  }
}

// ------------------------------ K5: PE dwconv (in-place add) ----------------
__global__ __launch_bounds__(256) void pe_kernel(
    const bf16* __restrict__ qkv, const float* __restrict__ pw,
    const float* __restrict__ bn, bf16* __restrict__ outa) {
  int tid = blockIdx.x * 256 + threadIdx.x;
  int n = tid & (N_ - 1), c = (tid >> 12) & 255, b = tid >> 20;
  int h = n >> 6, w = n & 63;
  // v channel for c = nh*32+kd lives at qkv channel nh*96+64+kd
  int oc = (c >> 5) * 96 + 64 + (c & 31);
  const bf16* v = qkv + ((size_t)b * O3_ + oc) * N_;
  const float* wc = pw + c * 9;
  float acc = 0.f;
#pragma unroll
  for (int dy = -1; dy <= 1; dy++) {
    int hh = h + dy;
    if ((unsigned)hh >= 64u) continue;
#pragma unroll
    for (int dx = -1; dx <= 1; dx++) {
      int ww = w + dx;
      if ((unsigned)ww >= 64u) continue;
      acc += (float)v[hh * 64 + ww] * wc[(dy + 1) * 3 + (dx + 1)];
    }
  }
  float sc = bn[c] * rsqrtf(bn[3 * C_ + c] + 1e-5f);
  float y = (acc - bn[2 * C_ + c]) * sc + bn[C_ + c];
  size_t o = ((size_t)b * C_ + c) * N_ + n;
  outa[o] = (bf16)((float)outa[o] + y);
}

// ------------------------------ K6: proj GEMM -------------------------------
__global__ __launch_bounds__(256) void proj_gemm_kernel(
    const bf16* __restrict__ hb, const float* __restrict__ w,
    const float* __restrict__ bn, float* __restrict__ out) {
  int nt = blockIdx.x * 128, ot = blockIdx.y * 128, b = blockIdx.z;
  __shared__ __align__(16) bf16 As[128][40];
  __shared__ __align__(16) bf16 Bs[128][40];
  int t = threadIdx.x, wave = t >> 6, lane = t & 63, quad = lane >> 4, l16 = lane & 15;
  int wm = (wave >> 1) * 64, wn = (wave & 1) * 64;
  f32x4 acc[4][4];
#pragma unroll
  for (int mi = 0; mi < 4; mi++)
#pragma unroll
    for (int ni = 0; ni < 4; ni++) acc[mi][ni] = (f32x4){0.f, 0.f, 0.f, 0.f};
  const bf16* hbb = hb + (size_t)b * C_ * N_;
  for (int k0 = 0; k0 < 256; k0 += 32) {
    __syncthreads();
#pragma unroll
    for (int i = 0; i < 4; i++) {  // A: projW fp32
      int f = t + i * 256;
      int o = f >> 3, cq = (f & 7) * 4;
      float4 v4 = *(const float4*)(w + (size_t)(ot + o) * C_ + k0 + cq);
      As[o][cq] = (bf16)v4.x; As[o][cq + 1] = (bf16)v4.y;
      As[o][cq + 2] = (bf16)v4.z; As[o][cq + 3] = (bf16)v4.w;
    }
#pragma unroll
    for (int i = 0; i < 2; i++) {  // B: bf16 input
      int f = t + i * 256;
      int c = f >> 4, nq = (f & 15) * 8;
      union { uint4 u; bf16 e[8]; } pk;
      pk.u = *(const uint4*)(hbb + (size_t)(k0 + c) * N_ + nt + nq);
#pragma unroll
      for (int j = 0; j < 8; j++) Bs[nq + j][c] = pk.e[j];
    }
    __syncthreads();
    bf16x8 af[4], bfv[4];
#pragma unroll
    for (int mi = 0; mi < 4; mi++)
      af[mi] = *(const bf16x8*)&As[wm + mi * 16 + l16][quad * 8];
#pragma unroll
    for (int ni = 0; ni < 4; ni++)
      bfv[ni] = *(const bf16x8*)&Bs[wn + ni * 16 + l16][quad * 8];
#pragma unroll
    for (int mi = 0; mi < 4; mi++)
#pragma unroll
      for (int ni = 0; ni < 4; ni++)
        acc[mi][ni] = MFMA16(af[mi], bfv[ni], acc[mi][ni]);
  }
  float* ob = out + (size_t)b * C_ * N_;
#pragma unroll
  for (int mi = 0; mi < 4; mi++) {
    int o0 = ot + wm + mi * 16 + quad * 4;
    float4 g4 = *(const float4*)(bn + 0 * C_ + o0);
    float4 b4 = *(const float4*)(bn + 1 * C_ + o0);
    float4 m4 = *(const float4*)(bn + 2 * C_ + o0);
    float4 v4 = *(const float4*)(bn + 3 * C_ + o0);
    float sc[4], sh[4];
    sc[0] = g4.x * rsqrtf(v4.x + 1e-5f); sh[0] = b4.x - m4.x * sc[0];
    sc[1] = g4.y * rsqrtf(v4.y + 1e-5f); sh[1] = b4.y - m4.y * sc[1];
    sc[2] = g4.z * rsqrtf(v4.z + 1e-5f); sh[2] = b4.z - m4.z * sc[2];
    sc[3] = g4.w * rsqrtf(v4.w + 1e-5f); sh[3] = b4.w - m4.w * sc[3];
#pragma unroll
    for (int ni = 0; ni < 4; ni++) {
      int n = nt + wn + ni * 16 + l16;
#pragma unroll
      for (int r = 0; r < 4; r++)
        ob[(size_t)(o0 + r) * N_ + n] = acc[mi][ni][r] * sc[r] + sh[r];
    }
  }
}

// ------------------------------ launcher -----------------------------------
extern "C" void kernel_launch(void* const* d_in, const int* in_sizes, int n_in,
                              void* d_out, int out_size, void* d_ws, size_t ws_size,
                              hipStream_t stream) {
  const float* x = (const float*)d_in[0];
  const float* qkv_w = (const float*)d_in[1];
  const float* qkv_bn = (const float*)d_in[2];
  const float* pe_w = (const float*)d_in[3];
  const float* pe_bn = (const float*)d_in[4];
  const float* proj_w = (const float*)d_in[5];
  const float* proj_bn = (const float*)d_in[6];
  const float* an_bias = (const float*)d_in[7];
  const float* na_bias = (const float*)d_in[8];
  const float* ah_bias = (const float*)d_in[9];
  const float* aw_bias = (const float*)d_in[10];
  const float* ha_bias = (const float*)d_in[11];
  const float* wa_bias = (const float*)d_in[12];

  char* ws = (char*)d_ws;
  bf16* qkvb = (bf16*)(ws + 0);              // 100,663,296
  float* pb = (float*)(ws + 100663296);      //   8,388,608
  float* ab = (float*)(ws + 109051904);      //   8,388,608
  bf16* aT = (bf16*)(ws + 117440512);        //     524,288
  bf16* attnT = (bf16*)(ws + 117964800);     //     524,288
  bf16* outa = (bf16*)(ws + 118489088);      //  33,554,432  -> 152,043,520 total

  bias_pb_kernel<<<8192, 256, 0, stream>>>(an_bias, ah_bias, aw_bias, pb);
  bias_ab_kernel<<<8192, 256, 0, stream>>>(na_bias, ha_bias, wa_bias, ab);
  qkv_gemm_kernel<<<dim3(32, 6, 16), 256, 0, stream>>>(x, qkv_w, qkv_bn, qkvb);
  pool_kernel<<<1024, 256, 0, stream>>>(qkvb, aT);
  attn1_kernel<<<128, 256, 0, stream>>>(qkvb, aT, pb, attnT);
  attn2_kernel<<<dim3(16, 128), 256, 0, stream>>>(qkvb, aT, attnT, ab, outa);
  pe_kernel<<<65536, 256, 0, stream>>>(qkvb, pe_w, pe_bn, outa);
  proj_gemm_kernel<<<dim3(32, 2, 16), 256, 0, stream>>>(outa, proj_w, proj_bn,
                                                        (float*)d_out);
}

// Round 4
// 530.092 us; speedup vs baseline: 1.2761x; 1.2761x over previous
//
#include <hip/hip_runtime.h>
#include <cmath>

// ---------------------------------------------------------------------------
// Agent-attention block, MI355X gfx950.
// qkv channel layout (reference reshape (B,NH,3KD,N)): per head nh,
//   q = channels nh*96 + [0,32), k = nh*96 + [32,64), v = nh*96 + [64,96).
// Workspace layout (143,654,912 B):
//   qT [b][nh][n][kd] bf16 (33.5MB) | kT same (33.5MB) | vv [b][c][n] bf16 (33.5MB)
//   pb [nh][g][n] bf16 (4MB) | ab [nh][n][g] bf16 (4MB)
//   aT (0.5MB) | attnT (0.5MB) | outa (33.5MB; first 17.8MB double as attn1 partials)
// Pipeline:
//   K0a/K0b biases -> K1 qkv GEMM (writes qT/kT transposed + vv)
//   K2 agent pooling -> K3 attn1 split-N (16x128 wgs, partials) -> K3b combine
//   K4 attn2 -> K5 pe dwconv (in-place) -> K6 proj GEMM
// ---------------------------------------------------------------------------

typedef __bf16 bf16;
typedef bf16 bf16x8 __attribute__((ext_vector_type(8)));
typedef float f32x4 __attribute__((ext_vector_type(4)));

__device__ __forceinline__ f32x4 MFMA16(bf16x8 a, bf16x8 b, f32x4 c) {
  return __builtin_amdgcn_mfma_f32_16x16x32_bf16(a, b, c, 0, 0, 0);
}

constexpr int B_ = 16, C_ = 256, N_ = 4096;
constexpr int NH_ = 8, KD_ = 32, AG_ = 64, O3_ = 768;
constexpr int PSTRIDE_ = 64 + 64 + 64 * 32;  // 2176 floats per (bh,tile) partial
constexpr float SCALE_ = 0.17677669529663687f;  // 32^-0.5

// ------------------------------ bias kernels -------------------------------
__device__ __forceinline__ float bilerp7(const float* __restrict__ A, int h, int w) {
  float fy = (h + 0.5f) * (7.0f / 64.0f) - 0.5f;
  float fx = (w + 0.5f) * (7.0f / 64.0f) - 0.5f;
  float fy0 = floorf(fy), fx0 = floorf(fx);
  float wy = fy - fy0, wx = fx - fx0;
  int y0 = (int)fy0, x0 = (int)fx0;
  int y0c = min(max(y0, 0), 6), y1c = min(max(y0 + 1, 0), 6);
  int x0c = min(max(x0, 0), 6), x1c = min(max(x0 + 1, 0), 6);
  float a00 = A[y0c * 7 + x0c], a01 = A[y0c * 7 + x1c];
  float a10 = A[y1c * 7 + x0c], a11 = A[y1c * 7 + x1c];
  return (1.0f - wy) * ((1.0f - wx) * a00 + wx * a01) +
         wy * ((1.0f - wx) * a10 + wx * a11);
}

__global__ __launch_bounds__(256) void bias_pb_kernel(
    const float* __restrict__ an, const float* __restrict__ ah,
    const float* __restrict__ aw, bf16* __restrict__ pb) {
  int tid = blockIdx.x * 256 + threadIdx.x;  // nh,g,n  (n fastest)
  int n = tid & (N_ - 1);
  int g = (tid >> 12) & 63;
  int nh = tid >> 18;
  int h = n >> 6, w = n & 63;
  float v = bilerp7(an + (nh * AG_ + g) * 49, h, w);
  pb[tid] = (bf16)(v + ah[(nh * AG_ + g) * 64 + h] + aw[(nh * AG_ + g) * 64 + w]);
}

__global__ __launch_bounds__(256) void bias_ab_kernel(
    const float* __restrict__ na, const float* __restrict__ ha,
    const float* __restrict__ wa, bf16* __restrict__ ab) {
  int tid = blockIdx.x * 256 + threadIdx.x;  // nh,n,g  (g fastest)
  int g = tid & 63;
  int n = (tid >> 6) & (N_ - 1);
  int nh = tid >> 18;
  int h = n >> 6, w = n & 63;
  float v = bilerp7(na + (nh * AG_ + g) * 49, h, w);
  ab[tid] = (bf16)(v + ha[(nh * 64 + h) * AG_ + g] + wa[(nh * 64 + w) * AG_ + g]);
}

// ------------------------------ K1: qkv GEMM -------------------------------
// Writes q,k transposed per-head [b][nh][n][kd]; v as [b][c][n] (c=nh*32+kd).
__global__ __launch_bounds__(256) void qkv_gemm_kernel(
    const float* __restrict__ x, const float* __restrict__ w,
    const float* __restrict__ bn, bf16* __restrict__ qT,
    bf16* __restrict__ kT, bf16* __restrict__ vv) {
  int nt = blockIdx.x * 128, ot = blockIdx.y * 128, b = blockIdx.z;
  __shared__ __align__(16) bf16 As[128][40];
  __shared__ __align__(16) bf16 Bs[128][40];
  int t = threadIdx.x, wave = t >> 6, lane = t & 63, quad = lane >> 4, l16 = lane & 15;
  int wm = (wave >> 1) * 64, wn = (wave & 1) * 64;
  f32x4 acc[4][4];
#pragma unroll
  for (int mi = 0; mi < 4; mi++)
#pragma unroll
    for (int ni = 0; ni < 4; ni++) acc[mi][ni] = (f32x4){0.f, 0.f, 0.f, 0.f};
  const float* xb = x + (size_t)b * C_ * N_;
  for (int k0 = 0; k0 < 256; k0 += 32) {
    __syncthreads();
#pragma unroll
    for (int i = 0; i < 4; i++) {  // A: W[ot..+128][k0..+32]
      int f = t + i * 256;
      int o = f >> 3, cq = (f & 7) * 4;
      float4 v4 = *(const float4*)(w + (size_t)(ot + o) * C_ + k0 + cq);
      As[o][cq] = (bf16)v4.x; As[o][cq + 1] = (bf16)v4.y;
      As[o][cq + 2] = (bf16)v4.z; As[o][cq + 3] = (bf16)v4.w;
    }
#pragma unroll
    for (int i = 0; i < 4; i++) {  // B: x[k0..+32][nt..+128] -> Bs[n][k]
      int f = t + i * 256;
      int c = f >> 5, nq = (f & 31) * 4;
      float4 v4 = *(const float4*)(xb + (size_t)(k0 + c) * N_ + nt + nq);
      Bs[nq][c] = (bf16)v4.x; Bs[nq + 1][c] = (bf16)v4.y;
      Bs[nq + 2][c] = (bf16)v4.z; Bs[nq + 3][c] = (bf16)v4.w;
    }
    __syncthreads();
    bf16x8 af[4], bfv[4];
#pragma unroll
    for (int mi = 0; mi < 4; mi++)
      af[mi] = *(const bf16x8*)&As[wm + mi * 16 + l16][quad * 8];
#pragma unroll
    for (int ni = 0; ni < 4; ni++)
      bfv[ni] = *(const bf16x8*)&Bs[wn + ni * 16 + l16][quad * 8];
#pragma unroll
    for (int mi = 0; mi < 4; mi++)
#pragma unroll
      for (int ni = 0; ni < 4; ni++)
        acc[mi][ni] = MFMA16(af[mi], bfv[ni], acc[mi][ni]);
  }
#pragma unroll
  for (int mi = 0; mi < 4; mi++) {
    int o0 = ot + wm + mi * 16 + quad * 4;
    float4 g4 = *(const float4*)(bn + 0 * O3_ + o0);
    float4 b4 = *(const float4*)(bn + 1 * O3_ + o0);
    float4 m4 = *(const float4*)(bn + 2 * O3_ + o0);
    float4 v4 = *(const float4*)(bn + 3 * O3_ + o0);
    float sc[4], sh[4];
    sc[0] = g4.x * rsqrtf(v4.x + 1e-5f); sh[0] = b4.x - m4.x * sc[0];
    sc[1] = g4.y * rsqrtf(v4.y + 1e-5f); sh[1] = b4.y - m4.y * sc[1];
    sc[2] = g4.z * rsqrtf(v4.z + 1e-5f); sh[2] = b4.z - m4.z * sc[2];
    sc[3] = g4.w * rsqrtf(v4.w + 1e-5f); sh[3] = b4.w - m4.w * sc[3];
    int base16 = ot + wm + mi * 16;              // wave-uniform, 16-aligned
    int nh = base16 / 96;
    int rem = base16 % 96;
    int type = rem >> 5;                          // 0=q, 1=k, 2=v
    int kdb = (rem & 31) + quad * 4;              // kd of r=0
    if (type < 2) {
      bf16* dst = (type == 0 ? qT : kT) + ((size_t)(b * NH_ + nh) * N_) * KD_;
#pragma unroll
      for (int ni = 0; ni < 4; ni++) {
        int n = nt + wn + ni * 16 + l16;
        union { ushort4 u; bf16 e[4]; } pk;
#pragma unroll
        for (int r = 0; r < 4; r++) pk.e[r] = (bf16)(acc[mi][ni][r] * sc[r] + sh[r]);
        *(ushort4*)(dst + (size_t)n * KD_ + kdb) = pk.u;
      }
    } else {
      bf16* dst = vv + ((size_t)(b * NH_ + nh) * KD_) * N_;
#pragma unroll
      for (int ni = 0; ni < 4; ni++) {
        int n = nt + wn + ni * 16 + l16;
#pragma unroll
        for (int r = 0; r < 4; r++)
          dst[(size_t)(kdb + r) * N_ + n] = (bf16)(acc[mi][ni][r] * sc[r] + sh[r]);
      }
    }
  }
}

// ------------------------------ K2: agent pooling --------------------------
// a[b][nh2][g][kd2] = (1/64) sum_{hi,wi} qT[b][ho][n1][(w_>>4)+hi*4],
//   w_ = wo*8+wi, n1 = ((w_&15)*4 + (c>>6))*64 + (c&63), c = nh2*32+kd2,
//   ho = g>>3, wo = g&7.
__global__ __launch_bounds__(256) void pool_kernel(
    const bf16* __restrict__ qT, bf16* __restrict__ aT) {
  int tid = blockIdx.x * 256 + threadIdx.x;  // (((b*8+nh2)*64+g)*32+kd2)
  int kd2 = tid & 31;
  int g = (tid >> 5) & 63;
  int nh2 = (tid >> 11) & 7;
  int b = tid >> 14;
  int c = nh2 * KD_ + kd2;
  int ho = g >> 3, wo = g & 7;
  int ww = c & 63, ch = c >> 6;
  const bf16* qb = qT + ((size_t)(b * NH_ + ho) * N_) * KD_;
  float s = 0.f;
#pragma unroll
  for (int wi = 0; wi < 8; wi++) {
    int w_ = wo * 8 + wi;
    int n1 = ((w_ & 15) * 4 + ch) * 64 + ww;
    int kdlo = w_ >> 4;
#pragma unroll
    for (int hi = 0; hi < 8; hi++)
      s += (float)qb[(size_t)n1 * KD_ + kdlo + hi * 4];
  }
  aT[tid] = (bf16)(s * (1.0f / 64.0f));
}

// ------------------------------ K3: attn1 split-N --------------------------
struct SM3comb { float m[4][64]; float l[4][64]; float o[4][64][32]; };
union SM3u { bf16 Ps[4][64][72]; SM3comb c; };

__global__ __launch_bounds__(256) void attn1_kernel(
    const bf16* __restrict__ kT, const bf16* __restrict__ vv,
    const bf16* __restrict__ aT, const bf16* __restrict__ pb,
    float* __restrict__ part) {
  __shared__ __align__(16) SM3u sm;
  int tile = blockIdx.x, bh = blockIdx.y, nh = bh & 7;
  int t = threadIdx.x, wave = t >> 6, lane = t & 63, quad = lane >> 4, l16 = lane & 15;
  const bf16* aTb = aT + (size_t)bh * (AG_ * KD_);
  const bf16* kb = kT + (size_t)bh * N_ * KD_;
  const bf16* vb = vv + (size_t)bh * KD_ * N_;
  const bf16* pbh = pb + (size_t)nh * AG_ * N_;
  int nloc = wave * 64, ng = tile * 256 + nloc;
  bf16x8 af[4], kf[4];
#pragma unroll
  for (int mi = 0; mi < 4; mi++)
    af[mi] = *(const bf16x8*)(aTb + (mi * 16 + l16) * KD_ + quad * 8);
#pragma unroll
  for (int ni = 0; ni < 4; ni++)
    kf[ni] = *(const bf16x8*)(kb + (size_t)(ng + ni * 16 + l16) * KD_ + quad * 8);
  float mrow[4][4], lrow[4][4];
  f32x4 zero4 = (f32x4){0.f, 0.f, 0.f, 0.f};
#pragma unroll
  for (int mi = 0; mi < 4; mi++) {
    f32x4 s[4];
#pragma unroll
    for (int ni = 0; ni < 4; ni++) s[ni] = MFMA16(af[mi], kf[ni], zero4);
    int g0 = mi * 16 + quad * 4;
#pragma unroll
    for (int ni = 0; ni < 4; ni++) {
      const bf16* p = pbh + (size_t)g0 * N_ + ng + ni * 16 + l16;
#pragma unroll
      for (int r = 0; r < 4; r++)
        s[ni][r] = s[ni][r] * SCALE_ + (float)p[(size_t)r * N_];
    }
#pragma unroll
    for (int r = 0; r < 4; r++) {
      float mx = fmaxf(fmaxf(s[0][r], s[1][r]), fmaxf(s[2][r], s[3][r]));
#pragma unroll
      for (int off = 1; off < 16; off <<= 1) mx = fmaxf(mx, __shfl_xor(mx, off));
      float rs = 0.f;
#pragma unroll
      for (int ni = 0; ni < 4; ni++) {
        float pv = __expf(s[ni][r] - mx);
        s[ni][r] = pv; rs += pv;
      }
#pragma unroll
      for (int off = 1; off < 16; off <<= 1) rs += __shfl_xor(rs, off);
      mrow[mi][r] = mx; lrow[mi][r] = rs;
    }
#pragma unroll
    for (int ni = 0; ni < 4; ni++)
#pragma unroll
      for (int r = 0; r < 4; r++)
        sm.Ps[wave][mi * 16 + quad * 4 + r][ni * 16 + l16] = (bf16)s[ni][r];
  }
  f32x4 oacc[4][2];
#pragma unroll
  for (int mi = 0; mi < 4; mi++) { oacc[mi][0] = zero4; oacc[mi][1] = zero4; }
#pragma unroll
  for (int ks = 0; ks < 2; ks++) {
    bf16x8 vf[2], pf[4];
#pragma unroll
    for (int ci = 0; ci < 2; ci++)
      vf[ci] = *(const bf16x8*)(vb + (size_t)(ci * 16 + l16) * N_ + ng + ks * 32 + quad * 8);
#pragma unroll
    for (int mi = 0; mi < 4; mi++)
      pf[mi] = *(const bf16x8*)&sm.Ps[wave][mi * 16 + l16][ks * 32 + quad * 8];
#pragma unroll
    for (int mi = 0; mi < 4; mi++)
#pragma unroll
      for (int ci = 0; ci < 2; ci++)
        oacc[mi][ci] = MFMA16(pf[mi], vf[ci], oacc[mi][ci]);
  }
  __syncthreads();  // all waves done reading Ps; union switches to comb
#pragma unroll
  for (int mi = 0; mi < 4; mi++)
#pragma unroll
    for (int r = 0; r < 4; r++) {
      int g = mi * 16 + quad * 4 + r;
      if (l16 == 0) { sm.c.m[wave][g] = mrow[mi][r]; sm.c.l[wave][g] = lrow[mi][r]; }
      sm.c.o[wave][g][l16] = oacc[mi][0][r];
      sm.c.o[wave][g][16 + l16] = oacc[mi][1][r];
    }
  __syncthreads();
  {
    int g = t >> 2, kd0 = (t & 3) * 8;
    float M = fmaxf(fmaxf(sm.c.m[0][g], sm.c.m[1][g]), fmaxf(sm.c.m[2][g], sm.c.m[3][g]));
    float ew[4], L = 0.f;
#pragma unroll
    for (int w2 = 0; w2 < 4; w2++) {
      ew[w2] = __expf(sm.c.m[w2][g] - M);
      L += sm.c.l[w2][g] * ew[w2];
    }
    float* pt = part + (size_t)(bh * 16 + tile) * PSTRIDE_;
    if ((t & 3) == 0) { pt[g] = M; pt[64 + g] = L; }
    float4 o0, o1;
    o0.x = o0.y = o0.z = o0.w = 0.f; o1 = o0;
#pragma unroll
    for (int w2 = 0; w2 < 4; w2++) {
      float e = ew[w2];
      const float* src = &sm.c.o[w2][g][kd0];
      o0.x += src[0] * e; o0.y += src[1] * e; o0.z += src[2] * e; o0.w += src[3] * e;
      o1.x += src[4] * e; o1.y += src[5] * e; o1.z += src[6] * e; o1.w += src[7] * e;
    }
    *(float4*)(pt + 128 + g * 32 + kd0) = o0;
    *(float4*)(pt + 128 + g * 32 + kd0 + 4) = o1;
  }
}

// ------------------------------ K3b: combine partials ----------------------
__global__ __launch_bounds__(256) void attn1_combine_kernel(
    const float* __restrict__ part, bf16* __restrict__ attnT) {
  int bh = blockIdx.x, t = threadIdx.x;
  int g = t >> 2, kd0 = (t & 3) * 8;
  const float* base = part + (size_t)bh * 16 * PSTRIDE_;
  float gm = -1e30f, L = 0.f;
  float o[8];
#pragma unroll
  for (int j = 0; j < 8; j++) o[j] = 0.f;
  for (int tl = 0; tl < 16; tl++) {
    const float* pt = base + tl * PSTRIDE_;
    float m = pt[g], l = pt[64 + g];
    float nm = fmaxf(gm, m);
    float a0 = __expf(gm - nm), a1 = __expf(m - nm);
    L = L * a0 + l * a1;
    float4 x0 = *(const float4*)(pt + 128 + g * 32 + kd0);
    float4 x1 = *(const float4*)(pt + 128 + g * 32 + kd0 + 4);
    o[0] = o[0] * a0 + x0.x * a1; o[1] = o[1] * a0 + x0.y * a1;
    o[2] = o[2] * a0 + x0.z * a1; o[3] = o[3] * a0 + x0.w * a1;
    o[4] = o[4] * a0 + x1.x * a1; o[5] = o[5] * a0 + x1.y * a1;
    o[6] = o[6] * a0 + x1.z * a1; o[7] = o[7] * a0 + x1.w * a1;
    gm = nm;
  }
  float inv = 1.0f / L;
  bf16* dst = attnT + (size_t)bh * (KD_ * AG_);
#pragma unroll
  for (int j = 0; j < 8; j++)
    dst[(kd0 + j) * AG_ + g] = (bf16)(o[j] * inv);
}

// ------------------------------ K4: stage 2 --------------------------------
__global__ __launch_bounds__(256) void attn2_kernel(
    const bf16* __restrict__ qT, const bf16* __restrict__ aT,
    const bf16* __restrict__ attnT, const bf16* __restrict__ ab,
    bf16* __restrict__ outa) {
  __shared__ __align__(16) bf16 Ps[4][64][72];
  int nt = blockIdx.x * 256;
  int bh = blockIdx.y, b = bh >> 3, nh = bh & 7;
  int t = threadIdx.x, wave = t >> 6, lane = t & 63, quad = lane >> 4, l16 = lane & 15;
  const bf16* qb = qT + (size_t)bh * N_ * KD_;
  const bf16* aTb = aT + (size_t)bh * (AG_ * KD_);
  const bf16* atb = attnT + (size_t)bh * (KD_ * AG_);
  bf16x8 afr[4], tfr[2][2];
#pragma unroll
  for (int gi = 0; gi < 4; gi++)
    afr[gi] = *(const bf16x8*)(aTb + (gi * 16 + l16) * KD_ + quad * 8);
#pragma unroll
  for (int ci = 0; ci < 2; ci++)
#pragma unroll
    for (int ks = 0; ks < 2; ks++)
      tfr[ci][ks] = *(const bf16x8*)(atb + (ci * 16 + l16) * AG_ + ks * 32 + quad * 8);
  const bf16* abh = ab + (size_t)nh * N_ * AG_;
  int nloc = wave * 64;
  f32x4 zero4 = (f32x4){0.f, 0.f, 0.f, 0.f};
#pragma unroll
  for (int mi = 0; mi < 4; mi++) {
    bf16x8 qf = *(const bf16x8*)(qb + (size_t)(nt + nloc + mi * 16 + l16) * KD_ + quad * 8);
    f32x4 s[4];
#pragma unroll
    for (int gi = 0; gi < 4; gi++)
      s[gi] = MFMA16(qf, afr[gi], zero4);
    int n0 = nt + nloc + mi * 16 + quad * 4;
#pragma unroll
    for (int gi = 0; gi < 4; gi++) {
      int g = gi * 16 + l16;
#pragma unroll
      for (int r = 0; r < 4; r++)
        s[gi][r] = s[gi][r] * SCALE_ + (float)abh[(size_t)(n0 + r) * AG_ + g];
    }
#pragma unroll
    for (int r = 0; r < 4; r++) {
      float mx = fmaxf(fmaxf(s[0][r], s[1][r]), fmaxf(s[2][r], s[3][r]));
#pragma unroll
      for (int off = 1; off < 16; off <<= 1) mx = fmaxf(mx, __shfl_xor(mx, off));
      float rs = 0.f;
#pragma unroll
      for (int gi = 0; gi < 4; gi++) {
        float p = __expf(s[gi][r] - mx);
        s[gi][r] = p; rs += p;
      }
#pragma unroll
      for (int off = 1; off < 16; off <<= 1) rs += __shfl_xor(rs, off);
      float inv = 1.0f / rs;
#pragma unroll
      for (int gi = 0; gi < 4; gi++) s[gi][r] *= inv;
    }
#pragma unroll
    for (int gi = 0; gi < 4; gi++)
#pragma unroll
      for (int r = 0; r < 4; r++)
        Ps[wave][mi * 16 + quad * 4 + r][gi * 16 + l16] = (bf16)s[gi][r];
  }
  __syncthreads();
  f32x4 O[4][2];
#pragma unroll
  for (int mi = 0; mi < 4; mi++) { O[mi][0] = zero4; O[mi][1] = zero4; }
#pragma unroll
  for (int ks = 0; ks < 2; ks++) {
    bf16x8 pf[4];
#pragma unroll
    for (int mi = 0; mi < 4; mi++)
      pf[mi] = *(const bf16x8*)&Ps[wave][mi * 16 + l16][ks * 32 + quad * 8];
#pragma unroll
    for (int mi = 0; mi < 4; mi++)
#pragma unroll
      for (int ci = 0; ci < 2; ci++)
        O[mi][ci] = MFMA16(pf[mi], tfr[ci][ks], O[mi][ci]);
  }
  bf16* ob = outa + (size_t)b * C_ * N_;
#pragma unroll
  for (int mi = 0; mi < 4; mi++) {
    int n0 = nt + nloc + mi * 16 + quad * 4;
#pragma unroll
    for (int ci = 0; ci < 2; ci++) {
      int c = nh * KD_ + ci * 16 + l16;
      union { ushort4 u; bf16 e[4]; } pk;
#pragma unroll
      for (int r = 0; r < 4; r++) pk.e[r] = (bf16)O[mi][ci][r];
      *(ushort4*)(ob + (size_t)c * N_ + n0) = pk.u;
    }
  }
}

// ------------------------------ K5: PE dwconv (in-place add) ----------------
__global__ __launch_bounds__(256) void pe_kernel(
    const bf16* __restrict__ vv, const float* __restrict__ pw,
    const float* __restrict__ bn, bf16* __restrict__ outa) {
  int tid = blockIdx.x * 256 + threadIdx.x;
  int n = tid & (N_ - 1), c = (tid >> 12) & 255, b = tid >> 20;
  int h = n >> 6, w = n & 63;
  const bf16* v = vv + ((size_t)b * C_ + c) * N_;
  const float* wc = pw + c * 9;
  float acc = 0.f;
#pragma unroll
  for (int dy = -1; dy <= 1; dy++) {
    int hh = h + dy;
    if ((unsigned)hh >= 64u) continue;
#pragma unroll
    for (int dx = -1; dx <= 1; dx++) {
      int ww = w + dx;
      if ((unsigned)ww >= 64u) continue;
      acc += (float)v[hh * 64 + ww] * wc[(dy + 1) * 3 + (dx + 1)];
    }
  }
  float sc = bn[c] * rsqrtf(bn[3 * C_ + c] + 1e-5f);
  float y = (acc - bn[2 * C_ + c]) * sc + bn[C_ + c];
  size_t o = ((size_t)b * C_ + c) * N_ + n;
  outa[o] = (bf16)((float)outa[o] + y);
}

// ------------------------------ K6: proj GEMM -------------------------------
__global__ __launch_bounds__(256) void proj_gemm_kernel(
    const bf16* __restrict__ hb, const float* __restrict__ w,
    const float* __restrict__ bn, float* __restrict__ out) {
  int nt = blockIdx.x * 128, ot = blockIdx.y * 128, b = blockIdx.z;
  __shared__ __align__(16) bf16 As[128][40];
  __shared__ __align__(16) bf16 Bs[128][40];
  int t = threadIdx.x, wave = t >> 6, lane = t & 63, quad = lane >> 4, l16 = lane & 15;
  int wm = (wave >> 1) * 64, wn = (wave & 1) * 64;
  f32x4 acc[4][4];
#pragma unroll
  for (int mi = 0; mi < 4; mi++)
#pragma unroll
    for (int ni = 0; ni < 4; ni++) acc[mi][ni] = (f32x4){0.f, 0.f, 0.f, 0.f};
  const bf16* hbb = hb + (size_t)b * C_ * N_;
  for (int k0 = 0; k0 < 256; k0 += 32) {
    __syncthreads();
#pragma unroll
    for (int i = 0; i < 4; i++) {  // A: projW fp32
      int f = t + i * 256;
      int o = f >> 3, cq = (f & 7) * 4;
      float4 v4 = *(const float4*)(w + (size_t)(ot + o) * C_ + k0 + cq);
      As[o][cq] = (bf16)v4.x; As[o][cq + 1] = (bf16)v4.y;
      As[o][cq + 2] = (bf16)v4.z; As[o][cq + 3] = (bf16)v4.w;
    }
#pragma unroll
    for (int i = 0; i < 2; i++) {  // B: bf16 input
      int f = t + i * 256;
      int c = f >> 4, nq = (f & 15) * 8;
      union { uint4 u; bf16 e[8]; } pk;
      pk.u = *(const uint4*)(hbb + (size_t)(k0 + c) * N_ + nt + nq);
#pragma unroll
      for (int j = 0; j < 8; j++) Bs[nq + j][c] = pk.e[j];
    }
    __syncthreads();
    bf16x8 af[4], bfv[4];
#pragma unroll
    for (int mi = 0; mi < 4; mi++)
      af[mi] = *(const bf16x8*)&As[wm + mi * 16 + l16][quad * 8];
#pragma unroll
    for (int ni = 0; ni < 4; ni++)
      bfv[ni] = *(const bf16x8*)&Bs[wn + ni * 16 + l16][quad * 8];
#pragma unroll
    for (int mi = 0; mi < 4; mi++)
#pragma unroll
      for (int ni = 0; ni < 4; ni++)
        acc[mi][ni] = MFMA16(af[mi], bfv[ni], acc[mi][ni]);
  }
  float* ob = out + (size_t)b * C_ * N_;
#pragma unroll
  for (int mi = 0; mi < 4; mi++) {
    int o0 = ot + wm + mi * 16 + quad * 4;
    float4 g4 = *(const float4*)(bn + 0 * C_ + o0);
    float4 b4 = *(const float4*)(bn + 1 * C_ + o0);
    float4 m4 = *(const float4*)(bn + 2 * C_ + o0);
    float4 v4 = *(const float4*)(bn + 3 * C_ + o0);
    float sc[4], sh[4];
    sc[0] = g4.x * rsqrtf(v4.x + 1e-5f); sh[0] = b4.x - m4.x * sc[0];
    sc[1] = g4.y * rsqrtf(v4.y + 1e-5f); sh[1] = b4.y - m4.y * sc[1];
    sc[2] = g4.z * rsqrtf(v4.z + 1e-5f); sh[2] = b4.z - m4.z * sc[2];
    sc[3] = g4.w * rsqrtf(v4.w + 1e-5f); sh[3] = b4.w - m4.w * sc[3];
#pragma unroll
    for (int ni = 0; ni < 4; ni++) {
      int n = nt + wn + ni * 16 + l16;
#pragma unroll
      for (int r = 0; r < 4; r++)
        ob[(size_t)(o0 + r) * N_ + n] = acc[mi][ni][r] * sc[r] + sh[r];
    }
  }
}

// ------------------------------ launcher -----------------------------------
extern "C" void kernel_launch(void* const* d_in, const int* in_sizes, int n_in,
                              void* d_out, int out_size, void* d_ws, size_t ws_size,
                              hipStream_t stream) {
  const float* x = (const float*)d_in[0];
  const float* qkv_w = (const float*)d_in[1];
  const float* qkv_bn = (const float*)d_in[2];
  const float* pe_w = (const float*)d_in[3];
  const float* pe_bn = (const float*)d_in[4];
  const float* proj_w = (const float*)d_in[5];
  const float* proj_bn = (const float*)d_in[6];
  const float* an_bias = (const float*)d_in[7];
  const float* na_bias = (const float*)d_in[8];
  const float* ah_bias = (const float*)d_in[9];
  const float* aw_bias = (const float*)d_in[10];
  const float* ha_bias = (const float*)d_in[11];
  const float* wa_bias = (const float*)d_in[12];

  char* ws = (char*)d_ws;
  bf16* qT = (bf16*)(ws + 0);                 //  33,554,432
  bf16* kT = (bf16*)(ws + 33554432);          //  33,554,432
  bf16* vv = (bf16*)(ws + 67108864);          //  33,554,432
  bf16* pb = (bf16*)(ws + 100663296);         //   4,194,304
  bf16* ab = (bf16*)(ws + 104857600);         //   4,194,304
  bf16* aT = (bf16*)(ws + 109051904);         //     524,288
  bf16* attnT = (bf16*)(ws + 109576192);      //     524,288
  bf16* outa = (bf16*)(ws + 110100480);       //  33,554,432 -> 143,654,912 total
  float* part = (float*)outa;                  // 17.8MB partials, dead before attn2

  bias_pb_kernel<<<8192, 256, 0, stream>>>(an_bias, ah_bias, aw_bias, pb);
  bias_ab_kernel<<<8192, 256, 0, stream>>>(na_bias, ha_bias, wa_bias, ab);
  qkv_gemm_kernel<<<dim3(32, 6, 16), 256, 0, stream>>>(x, qkv_w, qkv_bn, qT, kT, vv);
  pool_kernel<<<1024, 256, 0, stream>>>(qT, aT);
  attn1_kernel<<<dim3(16, 128), 256, 0, stream>>>(kT, vv, aT, pb, part);
  attn1_combine_kernel<<<128, 256, 0, stream>>>(part, attnT);
  attn2_kernel<<<dim3(16, 128), 256, 0, stream>>>(qT, aT, attnT, ab, outa);
  pe_kernel<<<65536, 256, 0, stream>>>(vv, pe_w, pe_bn, outa);
  proj_gemm_kernel<<<dim3(32, 2, 16), 256, 0, stream>>>(outa, proj_w, proj_bn,
                                                        (float*)d_out);
}

// Round 5
// 458.425 us; speedup vs baseline: 1.4756x; 1.1563x over previous
//
#include <hip/hip_runtime.h>
#include <cmath>

// ---------------------------------------------------------------------------
// Agent-attention block, MI355X gfx950.  Round 5: m97-style GEMMs.
// qkv channel layout (reference reshape (B,NH,3KD,N)): per head nh,
//   q = channels nh*96 + [0,32), k = nh*96 + [32,64), v = nh*96 + [64,96).
// Workspace (144,187,392 B):
//   qT[b][nh][n][kd] | kT same (later houT[b][n][c]) | vv[b][c][n]
//   pb bf16 | ab bf16 | aT | attnT | outa[b][c][n] (earlier xT[b][n][c] + part)
//   wqb bf16[768][256] | wpb bf16[256][256] | shq f32[768] | shp f32[256]
// Pipeline:
//   prep_w, biases, transpose_x -> qkv GEMM (global_load_lds staging)
//   pool -> attn1 split-N -> combine -> attn2 -> pe (in-place)
//   transpose_h -> proj GEMM
// ---------------------------------------------------------------------------

typedef __bf16 bf16;
typedef bf16 bf16x8 __attribute__((ext_vector_type(8)));
typedef float f32x4 __attribute__((ext_vector_type(4)));

__device__ __forceinline__ f32x4 MFMA16(bf16x8 a, bf16x8 b, f32x4 c) {
  return __builtin_amdgcn_mfma_f32_16x16x32_bf16(a, b, c, 0, 0, 0);
}

// async global->LDS, 16B per lane; LDS dst = base + lane*16 (wave-uniform base)
__device__ __forceinline__ void gll16(const bf16* g, bf16* l) {
  __builtin_amdgcn_global_load_lds(
      (const __attribute__((address_space(1))) void*)g,
      (__attribute__((address_space(3))) void*)l, 16, 0, 0);
}

constexpr int B_ = 16, C_ = 256, N_ = 4096;
constexpr int NH_ = 8, KD_ = 32, AG_ = 64, O3_ = 768;
constexpr int PSTRIDE_ = 64 + 64 + 64 * 32;  // 2176 floats per (bh,tile) partial
constexpr float SCALE_ = 0.17677669529663687f;  // 32^-0.5

// ------------------------- prep_w: BN-fold + bf16 --------------------------
__global__ __launch_bounds__(256) void prep_w_kernel(
    const float* __restrict__ qkv_w, const float* __restrict__ qkv_bn,
    const float* __restrict__ proj_w, const float* __restrict__ proj_bn,
    bf16* __restrict__ wqb, float* __restrict__ shq,
    bf16* __restrict__ wpb, float* __restrict__ shp) {
  int o = blockIdx.x, t = threadIdx.x;
  if (o < O3_) {
    float g = qkv_bn[o], bb = qkv_bn[O3_ + o], m = qkv_bn[2 * O3_ + o],
          v = qkv_bn[3 * O3_ + o];
    float s = g * rsqrtf(v + 1e-5f);
    wqb[(size_t)o * C_ + t] = (bf16)(qkv_w[(size_t)o * C_ + t] * s);
    if (t == 0) shq[o] = bb - m * s;
  } else {
    int p = o - O3_;
    float g = proj_bn[p], bb = proj_bn[C_ + p], m = proj_bn[2 * C_ + p],
          v = proj_bn[3 * C_ + p];
    float s = g * rsqrtf(v + 1e-5f);
    wpb[(size_t)p * C_ + t] = (bf16)(proj_w[(size_t)p * C_ + t] * s);
    if (t == 0) shp[p] = bb - m * s;
  }
}

// ------------------------------ bias kernels -------------------------------
__device__ __forceinline__ float bilerp7(const float* __restrict__ A, int h, int w) {
  float fy = (h + 0.5f) * (7.0f / 64.0f) - 0.5f;
  float fx = (w + 0.5f) * (7.0f / 64.0f) - 0.5f;
  float fy0 = floorf(fy), fx0 = floorf(fx);
  float wy = fy - fy0, wx = fx - fx0;
  int y0 = (int)fy0, x0 = (int)fx0;
  int y0c = min(max(y0, 0), 6), y1c = min(max(y0 + 1, 0), 6);
  int x0c = min(max(x0, 0), 6), x1c = min(max(x0 + 1, 0), 6);
  float a00 = A[y0c * 7 + x0c], a01 = A[y0c * 7 + x1c];
  float a10 = A[y1c * 7 + x0c], a11 = A[y1c * 7 + x1c];
  return (1.0f - wy) * ((1.0f - wx) * a00 + wx * a01) +
         wy * ((1.0f - wx) * a10 + wx * a11);
}

__global__ __launch_bounds__(256) void bias_pb_kernel(
    const float* __restrict__ an, const float* __restrict__ ah,
    const float* __restrict__ aw, bf16* __restrict__ pb) {
  int tid = blockIdx.x * 256 + threadIdx.x;  // nh,g,n  (n fastest)
  int n = tid & (N_ - 1);
  int g = (tid >> 12) & 63;
  int nh = tid >> 18;
  int h = n >> 6, w = n & 63;
  float v = bilerp7(an + (nh * AG_ + g) * 49, h, w);
  pb[tid] = (bf16)(v + ah[(nh * AG_ + g) * 64 + h] + aw[(nh * AG_ + g) * 64 + w]);
}

__global__ __launch_bounds__(256) void bias_ab_kernel(
    const float* __restrict__ na, const float* __restrict__ ha,
    const float* __restrict__ wa, bf16* __restrict__ ab) {
  int tid = blockIdx.x * 256 + threadIdx.x;  // nh,n,g  (g fastest)
  int g = tid & 63;
  int n = (tid >> 6) & (N_ - 1);
  int nh = tid >> 18;
  int h = n >> 6, w = n & 63;
  float v = bilerp7(na + (nh * AG_ + g) * 49, h, w);
  ab[tid] = (bf16)(v + ha[(nh * 64 + h) * AG_ + g] + wa[(nh * 64 + w) * AG_ + g]);
}

// --------------------- transpose_x: [c][n] f32 -> [n][c] bf16 --------------
__global__ __launch_bounds__(256) void transpose_x_kernel(
    const float* __restrict__ x, bf16* __restrict__ xT) {
  __shared__ __align__(16) unsigned LDSd[64 * 36];
  int b = blockIdx.x, n0 = blockIdx.y * 64, c0 = blockIdx.z * 64;
  int t = threadIdx.x, n = t & 63, cp = t >> 6;
  const float* xb = x + ((size_t)b * C_ + c0) * N_ + n0;
#pragma unroll
  for (int j = 0; j < 8; j++) {
    int cpr = cp * 8 + j;  // c-pair index 0..31
    int c = cpr * 2;
    float f0 = xb[(size_t)c * N_ + n];
    float f1 = xb[(size_t)(c + 1) * N_ + n];
    union { bf16 h[2]; unsigned u; } pk;
    pk.h[0] = (bf16)f0; pk.h[1] = (bf16)f1;
    LDSd[n * 36 + cpr] = pk.u;
  }
  __syncthreads();
  int n2 = t >> 2, seg = t & 3;
  const unsigned* row = &LDSd[n2 * 36 + seg * 8];
  uint4 d0 = *(const uint4*)row;
  uint4 d1 = *(const uint4*)(row + 4);
  bf16* dst = xT + ((size_t)b * N_ + n0 + n2) * C_ + c0 + seg * 16;
  *(uint4*)dst = d0;
  *(uint4*)(dst + 8) = d1;
}

// --------------------- transpose_h: [c][n] bf16 -> [n][c] bf16 -------------
__global__ __launch_bounds__(256) void transpose_h_kernel(
    const bf16* __restrict__ hb, bf16* __restrict__ hT) {
  __shared__ __align__(16) unsigned LDSd[64 * 36];
  int b = blockIdx.x, n0 = blockIdx.y * 64, c0 = blockIdx.z * 64;
  int t = threadIdx.x, n = t & 63, cp = t >> 6;
  const bf16* xb = hb + ((size_t)b * C_ + c0) * N_ + n0;
#pragma unroll
  for (int j = 0; j < 8; j++) {
    int cpr = cp * 8 + j;
    int c = cpr * 2;
    union { bf16 h[2]; unsigned u; } pk;
    pk.h[0] = xb[(size_t)c * N_ + n];
    pk.h[1] = xb[(size_t)(c + 1) * N_ + n];
    LDSd[n * 36 + cpr] = pk.u;
  }
  __syncthreads();
  int n2 = t >> 2, seg = t & 3;
  const unsigned* row = &LDSd[n2 * 36 + seg * 8];
  uint4 d0 = *(const uint4*)row;
  uint4 d1 = *(const uint4*)(row + 4);
  bf16* dst = hT + ((size_t)b * N_ + n0 + n2) * C_ + c0 + seg * 16;
  *(uint4*)dst = d0;
  *(uint4*)(dst + 8) = d1;
}

// ------------------------------ K1: qkv GEMM -------------------------------
// A = wqb [768][256] bf16 (BN-folded), B = xT [b][n][256] bf16.
// Writes q,k transposed per-head [b][nh][n][kd]; v as [b][c][n] (c=nh*32+kd).
__global__ __launch_bounds__(256) void qkv_gemm_kernel(
    const bf16* __restrict__ xT, const bf16* __restrict__ wqb,
    const float* __restrict__ shq, bf16* __restrict__ qT,
    bf16* __restrict__ kT, bf16* __restrict__ vv) {
  int nt = blockIdx.x * 128, ot = blockIdx.y * 128, b = blockIdx.z;
  __shared__ __align__(16) bf16 As[128][32];
  __shared__ __align__(16) bf16 Bs[128][32];
  int t = threadIdx.x, wave = t >> 6, lane = t & 63, quad = lane >> 4, l16 = lane & 15;
  int wm = (wave >> 1) * 64, wn = (wave & 1) * 64;
  int lr = lane >> 2, lc = (lane & 3) * 8;  // 4 lanes per 64B row
  f32x4 acc[4][4];
#pragma unroll
  for (int mi = 0; mi < 4; mi++)
#pragma unroll
    for (int ni = 0; ni < 4; ni++) acc[mi][ni] = (f32x4){0.f, 0.f, 0.f, 0.f};
  const bf16* xTb = xT + (size_t)b * N_ * C_;
  for (int k0 = 0; k0 < 256; k0 += 32) {
    __syncthreads();
#pragma unroll
    for (int i = 0; i < 2; i++) {
      int r0 = wave * 32 + i * 16;
      gll16(wqb + (size_t)(ot + r0 + lr) * C_ + k0 + lc, &As[r0][0]);
      gll16(xTb + (size_t)(nt + r0 + lr) * C_ + k0 + lc, &Bs[r0][0]);
    }
    __syncthreads();
    bf16x8 af[4], bfv[4];
#pragma unroll
    for (int mi = 0; mi < 4; mi++)
      af[mi] = *(const bf16x8*)&As[wm + mi * 16 + l16][quad * 8];
#pragma unroll
    for (int ni = 0; ni < 4; ni++)
      bfv[ni] = *(const bf16x8*)&Bs[wn + ni * 16 + l16][quad * 8];
#pragma unroll
    for (int mi = 0; mi < 4; mi++)
#pragma unroll
      for (int ni = 0; ni < 4; ni++)
        acc[mi][ni] = MFMA16(af[mi], bfv[ni], acc[mi][ni]);
  }
#pragma unroll
  for (int mi = 0; mi < 4; mi++) {
    int o0 = ot + wm + mi * 16 + quad * 4;
    float4 s4 = *(const float4*)(shq + o0);
    float sh[4] = {s4.x, s4.y, s4.z, s4.w};
    int base16 = ot + wm + mi * 16;  // wave-uniform, 16-aligned
    int nh = base16 / 96;
    int rem = base16 % 96;
    int type = rem >> 5;             // 0=q, 1=k, 2=v
    int kdb = (rem & 31) + quad * 4; // kd of r=0
    if (type < 2) {
      bf16* dst = (type == 0 ? qT : kT) + ((size_t)(b * NH_ + nh) * N_) * KD_;
#pragma unroll
      for (int ni = 0; ni < 4; ni++) {
        int n = nt + wn + ni * 16 + l16;
        union { ushort4 u; bf16 e[4]; } pk;
#pragma unroll
        for (int r = 0; r < 4; r++) pk.e[r] = (bf16)(acc[mi][ni][r] + sh[r]);
        *(ushort4*)(dst + (size_t)n * KD_ + kdb) = pk.u;
      }
    } else {
      bf16* dst = vv + ((size_t)(b * NH_ + nh) * KD_) * N_;
#pragma unroll
      for (int ni = 0; ni < 4; ni++) {
        int n = nt + wn + ni * 16 + l16;
#pragma unroll
        for (int r = 0; r < 4; r++)
          dst[(size_t)(kdb + r) * N_ + n] = (bf16)(acc[mi][ni][r] + sh[r]);
      }
    }
  }
}

// ------------------------------ K2: agent pooling --------------------------
__global__ __launch_bounds__(256) void pool_kernel(
    const bf16* __restrict__ qT, bf16* __restrict__ aT) {
  int tid = blockIdx.x * 256 + threadIdx.x;  // (((b*8+nh2)*64+g)*32+kd2)
  int kd2 = tid & 31;
  int g = (tid >> 5) & 63;
  int nh2 = (tid >> 11) & 7;
  int b = tid >> 14;
  int c = nh2 * KD_ + kd2;
  int ho = g >> 3, wo = g & 7;
  int ww = c & 63, ch = c >> 6;
  const bf16* qb = qT + ((size_t)(b * NH_ + ho) * N_) * KD_;
  float s = 0.f;
#pragma unroll
  for (int wi = 0; wi < 8; wi++) {
    int w_ = wo * 8 + wi;
    int n1 = ((w_ & 15) * 4 + ch) * 64 + ww;
    int kdlo = w_ >> 4;
#pragma unroll
    for (int hi = 0; hi < 8; hi++)
      s += (float)qb[(size_t)n1 * KD_ + kdlo + hi * 4];
  }
  aT[tid] = (bf16)(s * (1.0f / 64.0f));
}

// ------------------------------ K3: attn1 split-N --------------------------
struct SM3comb { float m[4][64]; float l[4][64]; float o[4][64][32]; };
union SM3u { bf16 Ps[4][64][72]; SM3comb c; };

__global__ __launch_bounds__(256) void attn1_kernel(
    const bf16* __restrict__ kT, const bf16* __restrict__ vv,
    const bf16* __restrict__ aT, const bf16* __restrict__ pb,
    float* __restrict__ part) {
  __shared__ __align__(16) SM3u sm;
  int tile = blockIdx.x, bh = blockIdx.y, nh = bh & 7;
  int t = threadIdx.x, wave = t >> 6, lane = t & 63, quad = lane >> 4, l16 = lane & 15;
  const bf16* aTb = aT + (size_t)bh * (AG_ * KD_);
  const bf16* kb = kT + (size_t)bh * N_ * KD_;
  const bf16* vb = vv + (size_t)bh * KD_ * N_;
  const bf16* pbh = pb + (size_t)nh * AG_ * N_;
  int nloc = wave * 64, ng = tile * 256 + nloc;
  bf16x8 af[4], kf[4];
#pragma unroll
  for (int mi = 0; mi < 4; mi++)
    af[mi] = *(const bf16x8*)(aTb + (mi * 16 + l16) * KD_ + quad * 8);
#pragma unroll
  for (int ni = 0; ni < 4; ni++)
    kf[ni] = *(const bf16x8*)(kb + (size_t)(ng + ni * 16 + l16) * KD_ + quad * 8);
  float mrow[4][4], lrow[4][4];
  f32x4 zero4 = (f32x4){0.f, 0.f, 0.f, 0.f};
#pragma unroll
  for (int mi = 0; mi < 4; mi++) {
    f32x4 s[4];
#pragma unroll
    for (int ni = 0; ni < 4; ni++) s[ni] = MFMA16(af[mi], kf[ni], zero4);
    int g0 = mi * 16 + quad * 4;
#pragma unroll
    for (int ni = 0; ni < 4; ni++) {
      const bf16* p = pbh + (size_t)g0 * N_ + ng + ni * 16 + l16;
#pragma unroll
      for (int r = 0; r < 4; r++)
        s[ni][r] = s[ni][r] * SCALE_ + (float)p[(size_t)r * N_];
    }
#pragma unroll
    for (int r = 0; r < 4; r++) {
      float mx = fmaxf(fmaxf(s[0][r], s[1][r]), fmaxf(s[2][r], s[3][r]));
#pragma unroll
      for (int off = 1; off < 16; off <<= 1) mx = fmaxf(mx, __shfl_xor(mx, off));
      float rs = 0.f;
#pragma unroll
      for (int ni = 0; ni < 4; ni++) {
        float pv = __expf(s[ni][r] - mx);
        s[ni][r] = pv; rs += pv;
      }
#pragma unroll
      for (int off = 1; off < 16; off <<= 1) rs += __shfl_xor(rs, off);
      mrow[mi][r] = mx; lrow[mi][r] = rs;
    }
#pragma unroll
    for (int ni = 0; ni < 4; ni++)
#pragma unroll
      for (int r = 0; r < 4; r++)
        sm.Ps[wave][mi * 16 + quad * 4 + r][ni * 16 + l16] = (bf16)s[ni][r];
  }
  f32x4 oacc[4][2];
#pragma unroll
  for (int mi = 0; mi < 4; mi++) { oacc[mi][0] = zero4; oacc[mi][1] = zero4; }
#pragma unroll
  for (int ks = 0; ks < 2; ks++) {
    bf16x8 vf[2], pf[4];
#pragma unroll
    for (int ci = 0; ci < 2; ci++)
      vf[ci] = *(const bf16x8*)(vb + (size_t)(ci * 16 + l16) * N_ + ng + ks * 32 + quad * 8);
#pragma unroll
    for (int mi = 0; mi < 4; mi++)
      pf[mi] = *(const bf16x8*)&sm.Ps[wave][mi * 16 + l16][ks * 32 + quad * 8];
#pragma unroll
    for (int mi = 0; mi < 4; mi++)
#pragma unroll
      for (int ci = 0; ci < 2; ci++)
        oacc[mi][ci] = MFMA16(pf[mi], vf[ci], oacc[mi][ci]);
  }
  __syncthreads();  // all waves done reading Ps; union switches to comb
#pragma unroll
  for (int mi = 0; mi < 4; mi++)
#pragma unroll
    for (int r = 0; r < 4; r++) {
      int g = mi * 16 + quad * 4 + r;
      if (l16 == 0) { sm.c.m[wave][g] = mrow[mi][r]; sm.c.l[wave][g] = lrow[mi][r]; }
      sm.c.o[wave][g][l16] = oacc[mi][0][r];
      sm.c.o[wave][g][16 + l16] = oacc[mi][1][r];
    }
  __syncthreads();
  {
    int g = t >> 2, kd0 = (t & 3) * 8;
    float M = fmaxf(fmaxf(sm.c.m[0][g], sm.c.m[1][g]), fmaxf(sm.c.m[2][g], sm.c.m[3][g]));
    float ew[4], L = 0.f;
#pragma unroll
    for (int w2 = 0; w2 < 4; w2++) {
      ew[w2] = __expf(sm.c.m[w2][g] - M);
      L += sm.c.l[w2][g] * ew[w2];
    }
    float* pt = part + (size_t)(bh * 16 + tile) * PSTRIDE_;
    if ((t & 3) == 0) { pt[g] = M; pt[64 + g] = L; }
    float4 o0, o1;
    o0.x = o0.y = o0.z = o0.w = 0.f; o1 = o0;
#pragma unroll
    for (int w2 = 0; w2 < 4; w2++) {
      float e = ew[w2];
      const float* src = &sm.c.o[w2][g][kd0];
      o0.x += src[0] * e; o0.y += src[1] * e; o0.z += src[2] * e; o0.w += src[3] * e;
      o1.x += src[4] * e; o1.y += src[5] * e; o1.z += src[6] * e; o1.w += src[7] * e;
    }
    *(float4*)(pt + 128 + g * 32 + kd0) = o0;
    *(float4*)(pt + 128 + g * 32 + kd0 + 4) = o1;
  }
}

// ------------------------------ K3b: combine partials ----------------------
__global__ __launch_bounds__(256) void attn1_combine_kernel(
    const float* __restrict__ part, bf16* __restrict__ attnT) {
  int bh = blockIdx.x, t = threadIdx.x;
  int g = t >> 2, kd0 = (t & 3) * 8;
  const float* base = part + (size_t)bh * 16 * PSTRIDE_;
  float gm = -1e30f, L = 0.f;
  float o[8];
#pragma unroll
  for (int j = 0; j < 8; j++) o[j] = 0.f;
  for (int tl = 0; tl < 16; tl++) {
    const float* pt = base + tl * PSTRIDE_;
    float m = pt[g], l = pt[64 + g];
    float nm = fmaxf(gm, m);
    float a0 = __expf(gm - nm), a1 = __expf(m - nm);
    L = L * a0 + l * a1;
    float4 x0 = *(const float4*)(pt + 128 + g * 32 + kd0);
    float4 x1 = *(const float4*)(pt + 128 + g * 32 + kd0 + 4);
    o[0] = o[0] * a0 + x0.x * a1; o[1] = o[1] * a0 + x0.y * a1;
    o[2] = o[2] * a0 + x0.z * a1; o[3] = o[3] * a0 + x0.w * a1;
    o[4] = o[4] * a0 + x1.x * a1; o[5] = o[5] * a0 + x1.y * a1;
    o[6] = o[6] * a0 + x1.z * a1; o[7] = o[7] * a0 + x1.w * a1;
    gm = nm;
  }
  float inv = 1.0f / L;
  bf16* dst = attnT + (size_t)bh * (KD_ * AG_);
#pragma unroll
  for (int j = 0; j < 8; j++)
    dst[(kd0 + j) * AG_ + g] = (bf16)(o[j] * inv);
}

// ------------------------------ K4: stage 2 --------------------------------
__global__ __launch_bounds__(256) void attn2_kernel(
    const bf16* __restrict__ qT, const bf16* __restrict__ aT,
    const bf16* __restrict__ attnT, const bf16* __restrict__ ab,
    bf16* __restrict__ outa) {
  __shared__ __align__(16) bf16 Ps[4][64][72];
  int nt = blockIdx.x * 256;
  int bh = blockIdx.y, b = bh >> 3, nh = bh & 7;
  int t = threadIdx.x, wave = t >> 6, lane = t & 63, quad = lane >> 4, l16 = lane & 15;
  const bf16* qb = qT + (size_t)bh * N_ * KD_;
  const bf16* aTb = aT + (size_t)bh * (AG_ * KD_);
  const bf16* atb = attnT + (size_t)bh * (KD_ * AG_);
  bf16x8 afr[4], tfr[2][2];
#pragma unroll
  for (int gi = 0; gi < 4; gi++)
    afr[gi] = *(const bf16x8*)(aTb + (gi * 16 + l16) * KD_ + quad * 8);
#pragma unroll
  for (int ci = 0; ci < 2; ci++)
#pragma unroll
    for (int ks = 0; ks < 2; ks++)
      tfr[ci][ks] = *(const bf16x8*)(atb + (ci * 16 + l16) * AG_ + ks * 32 + quad * 8);
  const bf16* abh = ab + (size_t)nh * N_ * AG_;
  int nloc = wave * 64;
  f32x4 zero4 = (f32x4){0.f, 0.f, 0.f, 0.f};
#pragma unroll
  for (int mi = 0; mi < 4; mi++) {
    bf16x8 qf = *(const bf16x8*)(qb + (size_t)(nt + nloc + mi * 16 + l16) * KD_ + quad * 8);
    f32x4 s[4];
#pragma unroll
    for (int gi = 0; gi < 4; gi++)
      s[gi] = MFMA16(qf, afr[gi], zero4);
    int n0 = nt + nloc + mi * 16 + quad * 4;
#pragma unroll
    for (int gi = 0; gi < 4; gi++) {
      int g = gi * 16 + l16;
#pragma unroll
      for (int r = 0; r < 4; r++)
        s[gi][r] = s[gi][r] * SCALE_ + (float)abh[(size_t)(n0 + r) * AG_ + g];
    }
#pragma unroll
    for (int r = 0; r < 4; r++) {
      float mx = fmaxf(fmaxf(s[0][r], s[1][r]), fmaxf(s[2][r], s[3][r]));
#pragma unroll
      for (int off = 1; off < 16; off <<= 1) mx = fmaxf(mx, __shfl_xor(mx, off));
      float rs = 0.f;
#pragma unroll
      for (int gi = 0; gi < 4; gi++) {
        float p = __expf(s[gi][r] - mx);
        s[gi][r] = p; rs += p;
      }
#pragma unroll
      for (int off = 1; off < 16; off <<= 1) rs += __shfl_xor(rs, off);
      float inv = 1.0f / rs;
#pragma unroll
      for (int gi = 0; gi < 4; gi++) s[gi][r] *= inv;
    }
#pragma unroll
    for (int gi = 0; gi < 4; gi++)
#pragma unroll
      for (int r = 0; r < 4; r++)
        Ps[wave][mi * 16 + quad * 4 + r][gi * 16 + l16] = (bf16)s[gi][r];
  }
  __syncthreads();
  f32x4 O[4][2];
#pragma unroll
  for (int mi = 0; mi < 4; mi++) { O[mi][0] = zero4; O[mi][1] = zero4; }
#pragma unroll
  for (int ks = 0; ks < 2; ks++) {
    bf16x8 pf[4];
#pragma unroll
    for (int mi = 0; mi < 4; mi++)
      pf[mi] = *(const bf16x8*)&Ps[wave][mi * 16 + l16][ks * 32 + quad * 8];
#pragma unroll
    for (int mi = 0; mi < 4; mi++)
#pragma unroll
      for (int ci = 0; ci < 2; ci++)
        O[mi][ci] = MFMA16(pf[mi], tfr[ci][ks], O[mi][ci]);
  }
  bf16* ob = outa + (size_t)b * C_ * N_;
#pragma unroll
  for (int mi = 0; mi < 4; mi++) {
    int n0 = nt + nloc + mi * 16 + quad * 4;
#pragma unroll
    for (int ci = 0; ci < 2; ci++) {
      int c = nh * KD_ + ci * 16 + l16;
      union { ushort4 u; bf16 e[4]; } pk;
#pragma unroll
      for (int r = 0; r < 4; r++) pk.e[r] = (bf16)O[mi][ci][r];
      *(ushort4*)(ob + (size_t)c * N_ + n0) = pk.u;
    }
  }
}

// ------------------------------ K5: PE dwconv (in-place add) ----------------
__global__ __launch_bounds__(256) void pe_kernel(
    const bf16* __restrict__ vv, const float* __restrict__ pw,
    const float* __restrict__ bn, bf16* __restrict__ outa) {
  int tid = blockIdx.x * 256 + threadIdx.x;
  int n = tid & (N_ - 1), c = (tid >> 12) & 255, b = tid >> 20;
  int h = n >> 6, w = n & 63;
  const bf16* v = vv + ((size_t)b * C_ + c) * N_;
  const float* wc = pw + c * 9;
  float acc = 0.f;
#pragma unroll
  for (int dy = -1; dy <= 1; dy++) {
    int hh = h + dy;
    if ((unsigned)hh >= 64u) continue;
#pragma unroll
    for (int dx = -1; dx <= 1; dx++) {
      int ww = w + dx;
      if ((unsigned)ww >= 64u) continue;
      acc += (float)v[hh * 64 + ww] * wc[(dy + 1) * 3 + (dx + 1)];
    }
  }
  float sc = bn[c] * rsqrtf(bn[3 * C_ + c] + 1e-5f);
  float y = (acc - bn[2 * C_ + c]) * sc + bn[C_ + c];
  size_t o = ((size_t)b * C_ + c) * N_ + n;
  outa[o] = (bf16)((float)outa[o] + y);
}

// ------------------------------ K6: proj GEMM -------------------------------
// A = wpb [256][256] bf16 (BN-folded), B = houT [b][n][256] bf16.
__global__ __launch_bounds__(256) void proj_gemm_kernel(
    const bf16* __restrict__ hT, const bf16* __restrict__ wpb,
    const float* __restrict__ shp, float* __restrict__ out) {
  int nt = blockIdx.x * 128, ot = blockIdx.y * 128, b = blockIdx.z;
  __shared__ __align__(16) bf16 As[128][32];
  __shared__ __align__(16) bf16 Bs[128][32];
  int t = threadIdx.x, wave = t >> 6, lane = t & 63, quad = lane >> 4, l16 = lane & 15;
  int wm = (wave >> 1) * 64, wn = (wave & 1) * 64;
  int lr = lane >> 2, lc = (lane & 3) * 8;
  f32x4 acc[4][4];
#pragma unroll
  for (int mi = 0; mi < 4; mi++)
#pragma unroll
    for (int ni = 0; ni < 4; ni++) acc[mi][ni] = (f32x4){0.f, 0.f, 0.f, 0.f};
  const bf16* hTb = hT + (size_t)b * N_ * C_;
  for (int k0 = 0; k0 < 256; k0 += 32) {
    __syncthreads();
#pragma unroll
    for (int i = 0; i < 2; i++) {
      int r0 = wave * 32 + i * 16;
      gll16(wpb + (size_t)(ot + r0 + lr) * C_ + k0 + lc, &As[r0][0]);
      gll16(hTb + (size_t)(nt + r0 + lr) * C_ + k0 + lc, &Bs[r0][0]);
    }
    __syncthreads();
    bf16x8 af[4], bfv[4];
#pragma unroll
    for (int mi = 0; mi < 4; mi++)
      af[mi] = *(const bf16x8*)&As[wm + mi * 16 + l16][quad * 8];
#pragma unroll
    for (int ni = 0; ni < 4; ni++)
      bfv[ni] = *(const bf16x8*)&Bs[wn + ni * 16 + l16][quad * 8];
#pragma unroll
    for (int mi = 0; mi < 4; mi++)
#pragma unroll
      for (int ni = 0; ni < 4; ni++)
        acc[mi][ni] = MFMA16(af[mi], bfv[ni], acc[mi][ni]);
  }
  float* ob = out + (size_t)b * C_ * N_;
#pragma unroll
  for (int mi = 0; mi < 4; mi++) {
    int o0 = ot + wm + mi * 16 + quad * 4;
    float4 s4 = *(const float4*)(shp + o0);
    float sh[4] = {s4.x, s4.y, s4.z, s4.w};
#pragma unroll
    for (int ni = 0; ni < 4; ni++) {
      int n = nt + wn + ni * 16 + l16;
#pragma unroll
      for (int r = 0; r < 4; r++)
        ob[(size_t)(o0 + r) * N_ + n] = acc[mi][ni][r] + sh[r];
    }
  }
}

// ------------------------------ launcher -----------------------------------
extern "C" void kernel_launch(void* const* d_in, const int* in_sizes, int n_in,
                              void* d_out, int out_size, void* d_ws, size_t ws_size,
                              hipStream_t stream) {
  const float* x = (const float*)d_in[0];
  const float* qkv_w = (const float*)d_in[1];
  const float* qkv_bn = (const float*)d_in[2];
  const float* pe_w = (const float*)d_in[3];
  const float* pe_bn = (const float*)d_in[4];
  const float* proj_w = (const float*)d_in[5];
  const float* proj_bn = (const float*)d_in[6];
  const float* an_bias = (const float*)d_in[7];
  const float* na_bias = (const float*)d_in[8];
  const float* ah_bias = (const float*)d_in[9];
  const float* aw_bias = (const float*)d_in[10];
  const float* ha_bias = (const float*)d_in[11];
  const float* wa_bias = (const float*)d_in[12];

  char* ws = (char*)d_ws;
  bf16* qT = (bf16*)(ws + 0);                 //  33,554,432
  bf16* kT = (bf16*)(ws + 33554432);          //  33,554,432 (later houT)
  bf16* vv = (bf16*)(ws + 67108864);          //  33,554,432
  bf16* pb = (bf16*)(ws + 100663296);         //   4,194,304
  bf16* ab = (bf16*)(ws + 104857600);         //   4,194,304
  bf16* aT = (bf16*)(ws + 109051904);         //     524,288
  bf16* attnT = (bf16*)(ws + 109576192);      //     524,288
  bf16* outa = (bf16*)(ws + 110100480);       //  33,554,432 (earlier xT + part)
  bf16* wqb = (bf16*)(ws + 143654912);        //     393,216
  bf16* wpb = (bf16*)(ws + 144048128);        //     131,072
  float* shq = (float*)(ws + 144179200);      //       4,096
  float* shp = (float*)(ws + 144183296);      //       4,096 -> 144,187,392
  bf16* xT = outa;                             // alias: dead before attn1
  bf16* houT = kT;                             // alias: kT dead after attn1
  float* part = (float*)outa;                  // partials, dead before attn2

  prep_w_kernel<<<1024, 256, 0, stream>>>(qkv_w, qkv_bn, proj_w, proj_bn,
                                          wqb, shq, wpb, shp);
  bias_pb_kernel<<<8192, 256, 0, stream>>>(an_bias, ah_bias, aw_bias, pb);
  bias_ab_kernel<<<8192, 256, 0, stream>>>(na_bias, ha_bias, wa_bias, ab);
  transpose_x_kernel<<<dim3(16, 64, 4), 256, 0, stream>>>(x, xT);
  qkv_gemm_kernel<<<dim3(32, 6, 16), 256, 0, stream>>>(xT, wqb, shq, qT, kT, vv);
  pool_kernel<<<1024, 256, 0, stream>>>(qT, aT);
  attn1_kernel<<<dim3(16, 128), 256, 0, stream>>>(kT, vv, aT, pb, part);
  attn1_combine_kernel<<<128, 256, 0, stream>>>(part, attnT);
  attn2_kernel<<<dim3(16, 128), 256, 0, stream>>>(qT, aT, attnT, ab, outa);
  pe_kernel<<<65536, 256, 0, stream>>>(vv, pe_w, pe_bn, outa);
  transpose_h_kernel<<<dim3(16, 64, 4), 256, 0, stream>>>(outa, houT);
  proj_gemm_kernel<<<dim3(32, 2, 16), 256, 0, stream>>>(houT, wpb, shp,
                                                        (float*)d_out);
}

// Round 6
// 390.203 us; speedup vs baseline: 1.7335x; 1.1748x over previous
//
#include <hip/hip_runtime.h>
#include <cmath>

// ---------------------------------------------------------------------------
// Agent-attention block, MI355X gfx950.  Round 6: fuse pe dwconv + transpose.
// qkv channel layout (reference reshape (B,NH,3KD,N)): per head nh,
//   q = channels nh*96 + [0,32), k = nh*96 + [32,64), v = nh*96 + [64,96).
// Workspace (144,187,392 B):
//   qT[b][nh][n][kd] | kT same (later houT[b][n][c]) | vv[b][c][n]
//   pb bf16 | ab bf16 | aT | attnT | outa[b][c][n] (earlier xT[b][n][c] + part)
//   wqb bf16[768][256] | wpb bf16[256][256] | shq f32[768] | shp f32[256]
// Pipeline:
//   prep_w, biases, transpose_x -> qkv GEMM (global_load_lds staging)
//   pool -> attn1 split-N -> combine -> attn2(outa)
//   pe_tr: houT[n][c] = outa[c][n] + BN(dwconv3x3(vv))   (fused, no LDS)
//   proj GEMM(houT)
// ---------------------------------------------------------------------------

typedef __bf16 bf16;
typedef bf16 bf16x8 __attribute__((ext_vector_type(8)));
typedef float f32x4 __attribute__((ext_vector_type(4)));

__device__ __forceinline__ f32x4 MFMA16(bf16x8 a, bf16x8 b, f32x4 c) {
  return __builtin_amdgcn_mfma_f32_16x16x32_bf16(a, b, c, 0, 0, 0);
}

// async global->LDS, 16B per lane; LDS dst = base + lane*16 (wave-uniform base)
__device__ __forceinline__ void gll16(const bf16* g, bf16* l) {
  __builtin_amdgcn_global_load_lds(
      (const __attribute__((address_space(1))) void*)g,
      (__attribute__((address_space(3))) void*)l, 16, 0, 0);
}

constexpr int B_ = 16, C_ = 256, N_ = 4096;
constexpr int NH_ = 8, KD_ = 32, AG_ = 64, O3_ = 768;
constexpr int PSTRIDE_ = 64 + 64 + 64 * 32;  // 2176 floats per (bh,tile) partial
constexpr float SCALE_ = 0.17677669529663687f;  // 32^-0.5

// ------------------------- prep_w: BN-fold + bf16 --------------------------
__global__ __launch_bounds__(256) void prep_w_kernel(
    const float* __restrict__ qkv_w, const float* __restrict__ qkv_bn,
    const float* __restrict__ proj_w, const float* __restrict__ proj_bn,
    bf16* __restrict__ wqb, float* __restrict__ shq,
    bf16* __restrict__ wpb, float* __restrict__ shp) {
  int o = blockIdx.x, t = threadIdx.x;
  if (o < O3_) {
    float g = qkv_bn[o], bb = qkv_bn[O3_ + o], m = qkv_bn[2 * O3_ + o],
          v = qkv_bn[3 * O3_ + o];
    float s = g * rsqrtf(v + 1e-5f);
    wqb[(size_t)o * C_ + t] = (bf16)(qkv_w[(size_t)o * C_ + t] * s);
    if (t == 0) shq[o] = bb - m * s;
  } else {
    int p = o - O3_;
    float g = proj_bn[p], bb = proj_bn[C_ + p], m = proj_bn[2 * C_ + p],
          v = proj_bn[3 * C_ + p];
    float s = g * rsqrtf(v + 1e-5f);
    wpb[(size_t)p * C_ + t] = (bf16)(proj_w[(size_t)p * C_ + t] * s);
    if (t == 0) shp[p] = bb - m * s;
  }
}

// ------------------------------ bias kernels -------------------------------
__device__ __forceinline__ float bilerp7(const float* __restrict__ A, int h, int w) {
  float fy = (h + 0.5f) * (7.0f / 64.0f) - 0.5f;
  float fx = (w + 0.5f) * (7.0f / 64.0f) - 0.5f;
  float fy0 = floorf(fy), fx0 = floorf(fx);
  float wy = fy - fy0, wx = fx - fx0;
  int y0 = (int)fy0, x0 = (int)fx0;
  int y0c = min(max(y0, 0), 6), y1c = min(max(y0 + 1, 0), 6);
  int x0c = min(max(x0, 0), 6), x1c = min(max(x0 + 1, 0), 6);
  float a00 = A[y0c * 7 + x0c], a01 = A[y0c * 7 + x1c];
  float a10 = A[y1c * 7 + x0c], a11 = A[y1c * 7 + x1c];
  return (1.0f - wy) * ((1.0f - wx) * a00 + wx * a01) +
         wy * ((1.0f - wx) * a10 + wx * a11);
}

__global__ __launch_bounds__(256) void bias_pb_kernel(
    const float* __restrict__ an, const float* __restrict__ ah,
    const float* __restrict__ aw, bf16* __restrict__ pb) {
  int tid = blockIdx.x * 256 + threadIdx.x;  // nh,g,n  (n fastest)
  int n = tid & (N_ - 1);
  int g = (tid >> 12) & 63;
  int nh = tid >> 18;
  int h = n >> 6, w = n & 63;
  float v = bilerp7(an + (nh * AG_ + g) * 49, h, w);
  pb[tid] = (bf16)(v + ah[(nh * AG_ + g) * 64 + h] + aw[(nh * AG_ + g) * 64 + w]);
}

__global__ __launch_bounds__(256) void bias_ab_kernel(
    const float* __restrict__ na, const float* __restrict__ ha,
    const float* __restrict__ wa, bf16* __restrict__ ab) {
  int tid = blockIdx.x * 256 + threadIdx.x;  // nh,n,g  (g fastest)
  int g = tid & 63;
  int n = (tid >> 6) & (N_ - 1);
  int nh = tid >> 18;
  int h = n >> 6, w = n & 63;
  float v = bilerp7(na + (nh * AG_ + g) * 49, h, w);
  ab[tid] = (bf16)(v + ha[(nh * 64 + h) * AG_ + g] + wa[(nh * 64 + w) * AG_ + g]);
}

// --------------------- transpose_x: [c][n] f32 -> [n][c] bf16 --------------
__global__ __launch_bounds__(256) void transpose_x_kernel(
    const float* __restrict__ x, bf16* __restrict__ xT) {
  __shared__ __align__(16) unsigned LDSd[64 * 36];
  int b = blockIdx.x, n0 = blockIdx.y * 64, c0 = blockIdx.z * 64;
  int t = threadIdx.x, n = t & 63, cp = t >> 6;
  const float* xb = x + ((size_t)b * C_ + c0) * N_ + n0;
#pragma unroll
  for (int j = 0; j < 8; j++) {
    int cpr = cp * 8 + j;  // c-pair index 0..31
    int c = cpr * 2;
    float f0 = xb[(size_t)c * N_ + n];
    float f1 = xb[(size_t)(c + 1) * N_ + n];
    union { bf16 h[2]; unsigned u; } pk;
    pk.h[0] = (bf16)f0; pk.h[1] = (bf16)f1;
    LDSd[n * 36 + cpr] = pk.u;
  }
  __syncthreads();
  int n2 = t >> 2, seg = t & 3;
  const unsigned* row = &LDSd[n2 * 36 + seg * 8];
  uint4 d0 = *(const uint4*)row;
  uint4 d1 = *(const uint4*)(row + 4);
  bf16* dst = xT + ((size_t)b * N_ + n0 + n2) * C_ + c0 + seg * 16;
  *(uint4*)dst = d0;
  *(uint4*)(dst + 8) = d1;
}

// ------------------------------ K1: qkv GEMM -------------------------------
// A = wqb [768][256] bf16 (BN-folded), B = xT [b][n][256] bf16.
// Writes q,k transposed per-head [b][nh][n][kd]; v as [b][c][n] (c=nh*32+kd).
__global__ __launch_bounds__(256) void qkv_gemm_kernel(
    const bf16* __restrict__ xT, const bf16* __restrict__ wqb,
    const float* __restrict__ shq, bf16* __restrict__ qT,
    bf16* __restrict__ kT, bf16* __restrict__ vv) {
  int nt = blockIdx.x * 128, ot = blockIdx.y * 128, b = blockIdx.z;
  __shared__ __align__(16) bf16 As[128][32];
  __shared__ __align__(16) bf16 Bs[128][32];
  int t = threadIdx.x, wave = t >> 6, lane = t & 63, quad = lane >> 4, l16 = lane & 15;
  int wm = (wave >> 1) * 64, wn = (wave & 1) * 64;
  int lr = lane >> 2, lc = (lane & 3) * 8;  // 4 lanes per 64B row
  f32x4 acc[4][4];
#pragma unroll
  for (int mi = 0; mi < 4; mi++)
#pragma unroll
    for (int ni = 0; ni < 4; ni++) acc[mi][ni] = (f32x4){0.f, 0.f, 0.f, 0.f};
  const bf16* xTb = xT + (size_t)b * N_ * C_;
  for (int k0 = 0; k0 < 256; k0 += 32) {
    __syncthreads();
#pragma unroll
    for (int i = 0; i < 2; i++) {
      int r0 = wave * 32 + i * 16;
      gll16(wqb + (size_t)(ot + r0 + lr) * C_ + k0 + lc, &As[r0][0]);
      gll16(xTb + (size_t)(nt + r0 + lr) * C_ + k0 + lc, &Bs[r0][0]);
    }
    __syncthreads();
    bf16x8 af[4], bfv[4];
#pragma unroll
    for (int mi = 0; mi < 4; mi++)
      af[mi] = *(const bf16x8*)&As[wm + mi * 16 + l16][quad * 8];
#pragma unroll
    for (int ni = 0; ni < 4; ni++)
      bfv[ni] = *(const bf16x8*)&Bs[wn + ni * 16 + l16][quad * 8];
#pragma unroll
    for (int mi = 0; mi < 4; mi++)
#pragma unroll
      for (int ni = 0; ni < 4; ni++)
        acc[mi][ni] = MFMA16(af[mi], bfv[ni], acc[mi][ni]);
  }
#pragma unroll
  for (int mi = 0; mi < 4; mi++) {
    int o0 = ot + wm + mi * 16 + quad * 4;
    float4 s4 = *(const float4*)(shq + o0);
    float sh[4] = {s4.x, s4.y, s4.z, s4.w};
    int base16 = ot + wm + mi * 16;  // wave-uniform, 16-aligned
    int nh = base16 / 96;
    int rem = base16 % 96;
    int type = rem >> 5;             // 0=q, 1=k, 2=v
    int kdb = (rem & 31) + quad * 4; // kd of r=0
    if (type < 2) {
      bf16* dst = (type == 0 ? qT : kT) + ((size_t)(b * NH_ + nh) * N_) * KD_;
#pragma unroll
      for (int ni = 0; ni < 4; ni++) {
        int n = nt + wn + ni * 16 + l16;
        union { ushort4 u; bf16 e[4]; } pk;
#pragma unroll
        for (int r = 0; r < 4; r++) pk.e[r] = (bf16)(acc[mi][ni][r] + sh[r]);
        *(ushort4*)(dst + (size_t)n * KD_ + kdb) = pk.u;
      }
    } else {
      bf16* dst = vv + ((size_t)(b * NH_ + nh) * KD_) * N_;
#pragma unroll
      for (int ni = 0; ni < 4; ni++) {
        int n = nt + wn + ni * 16 + l16;
#pragma unroll
        for (int r = 0; r < 4; r++)
          dst[(size_t)(kdb + r) * N_ + n] = (bf16)(acc[mi][ni][r] + sh[r]);
      }
    }
  }
}

// ------------------------------ K2: agent pooling --------------------------
__global__ __launch_bounds__(256) void pool_kernel(
    const bf16* __restrict__ qT, bf16* __restrict__ aT) {
  int tid = blockIdx.x * 256 + threadIdx.x;  // (((b*8+nh2)*64+g)*32+kd2)
  int kd2 = tid & 31;
  int g = (tid >> 5) & 63;
  int nh2 = (tid >> 11) & 7;
  int b = tid >> 14;
  int c = nh2 * KD_ + kd2;
  int ho = g >> 3, wo = g & 7;
  int ww = c & 63, ch = c >> 6;
  const bf16* qb = qT + ((size_t)(b * NH_ + ho) * N_) * KD_;
  float s = 0.f;
#pragma unroll
  for (int wi = 0; wi < 8; wi++) {
    int w_ = wo * 8 + wi;
    int n1 = ((w_ & 15) * 4 + ch) * 64 + ww;
    int kdlo = w_ >> 4;
#pragma unroll
    for (int hi = 0; hi < 8; hi++)
      s += (float)qb[(size_t)n1 * KD_ + kdlo + hi * 4];
  }
  aT[tid] = (bf16)(s * (1.0f / 64.0f));
}

// ------------------------------ K3: attn1 split-N --------------------------
struct SM3comb { float m[4][64]; float l[4][64]; float o[4][64][32]; };
union SM3u { bf16 Ps[4][64][72]; SM3comb c; };

__global__ __launch_bounds__(256) void attn1_kernel(
    const bf16* __restrict__ kT, const bf16* __restrict__ vv,
    const bf16* __restrict__ aT, const bf16* __restrict__ pb,
    float* __restrict__ part) {
  __shared__ __align__(16) SM3u sm;
  int tile = blockIdx.x, bh = blockIdx.y, nh = bh & 7;
  int t = threadIdx.x, wave = t >> 6, lane = t & 63, quad = lane >> 4, l16 = lane & 15;
  const bf16* aTb = aT + (size_t)bh * (AG_ * KD_);
  const bf16* kb = kT + (size_t)bh * N_ * KD_;
  const bf16* vb = vv + (size_t)bh * KD_ * N_;
  const bf16* pbh = pb + (size_t)nh * AG_ * N_;
  int nloc = wave * 64, ng = tile * 256 + nloc;
  bf16x8 af[4], kf[4];
#pragma unroll
  for (int mi = 0; mi < 4; mi++)
    af[mi] = *(const bf16x8*)(aTb + (mi * 16 + l16) * KD_ + quad * 8);
#pragma unroll
  for (int ni = 0; ni < 4; ni++)
    kf[ni] = *(const bf16x8*)(kb + (size_t)(ng + ni * 16 + l16) * KD_ + quad * 8);
  float mrow[4][4], lrow[4][4];
  f32x4 zero4 = (f32x4){0.f, 0.f, 0.f, 0.f};
#pragma unroll
  for (int mi = 0; mi < 4; mi++) {
    f32x4 s[4];
#pragma unroll
    for (int ni = 0; ni < 4; ni++) s[ni] = MFMA16(af[mi], kf[ni], zero4);
    int g0 = mi * 16 + quad * 4;
#pragma unroll
    for (int ni = 0; ni < 4; ni++) {
      const bf16* p = pbh + (size_t)g0 * N_ + ng + ni * 16 + l16;
#pragma unroll
      for (int r = 0; r < 4; r++)
        s[ni][r] = s[ni][r] * SCALE_ + (float)p[(size_t)r * N_];
    }
#pragma unroll
    for (int r = 0; r < 4; r++) {
      float mx = fmaxf(fmaxf(s[0][r], s[1][r]), fmaxf(s[2][r], s[3][r]));
#pragma unroll
      for (int off = 1; off < 16; off <<= 1) mx = fmaxf(mx, __shfl_xor(mx, off));
      float rs = 0.f;
#pragma unroll
      for (int ni = 0; ni < 4; ni++) {
        float pv = __expf(s[ni][r] - mx);
        s[ni][r] = pv; rs += pv;
      }
#pragma unroll
      for (int off = 1; off < 16; off <<= 1) rs += __shfl_xor(rs, off);
      mrow[mi][r] = mx; lrow[mi][r] = rs;
    }
#pragma unroll
    for (int ni = 0; ni < 4; ni++)
#pragma unroll
      for (int r = 0; r < 4; r++)
        sm.Ps[wave][mi * 16 + quad * 4 + r][ni * 16 + l16] = (bf16)s[ni][r];
  }
  f32x4 oacc[4][2];
#pragma unroll
  for (int mi = 0; mi < 4; mi++) { oacc[mi][0] = zero4; oacc[mi][1] = zero4; }
#pragma unroll
  for (int ks = 0; ks < 2; ks++) {
    bf16x8 vf[2], pf[4];
#pragma unroll
    for (int ci = 0; ci < 2; ci++)
      vf[ci] = *(const bf16x8*)(vb + (size_t)(ci * 16 + l16) * N_ + ng + ks * 32 + quad * 8);
#pragma unroll
    for (int mi = 0; mi < 4; mi++)
      pf[mi] = *(const bf16x8*)&sm.Ps[wave][mi * 16 + l16][ks * 32 + quad * 8];
#pragma unroll
    for (int mi = 0; mi < 4; mi++)
#pragma unroll
      for (int ci = 0; ci < 2; ci++)
        oacc[mi][ci] = MFMA16(pf[mi], vf[ci], oacc[mi][ci]);
  }
  __syncthreads();  // all waves done reading Ps; union switches to comb
#pragma unroll
  for (int mi = 0; mi < 4; mi++)
#pragma unroll
    for (int r = 0; r < 4; r++) {
      int g = mi * 16 + quad * 4 + r;
      if (l16 == 0) { sm.c.m[wave][g] = mrow[mi][r]; sm.c.l[wave][g] = lrow[mi][r]; }
      sm.c.o[wave][g][l16] = oacc[mi][0][r];
      sm.c.o[wave][g][16 + l16] = oacc[mi][1][r];
    }
  __syncthreads();
  {
    int g = t >> 2, kd0 = (t & 3) * 8;
    float M = fmaxf(fmaxf(sm.c.m[0][g], sm.c.m[1][g]), fmaxf(sm.c.m[2][g], sm.c.m[3][g]));
    float ew[4], L = 0.f;
#pragma unroll
    for (int w2 = 0; w2 < 4; w2++) {
      ew[w2] = __expf(sm.c.m[w2][g] - M);
      L += sm.c.l[w2][g] * ew[w2];
    }
    float* pt = part + (size_t)(bh * 16 + tile) * PSTRIDE_;
    if ((t & 3) == 0) { pt[g] = M; pt[64 + g] = L; }
    float4 o0, o1;
    o0.x = o0.y = o0.z = o0.w = 0.f; o1 = o0;
#pragma unroll
    for (int w2 = 0; w2 < 4; w2++) {
      float e = ew[w2];
      const float* src = &sm.c.o[w2][g][kd0];
      o0.x += src[0] * e; o0.y += src[1] * e; o0.z += src[2] * e; o0.w += src[3] * e;
      o1.x += src[4] * e; o1.y += src[5] * e; o1.z += src[6] * e; o1.w += src[7] * e;
    }
    *(float4*)(pt + 128 + g * 32 + kd0) = o0;
    *(float4*)(pt + 128 + g * 32 + kd0 + 4) = o1;
  }
}

// ------------------------------ K3b: combine partials ----------------------
__global__ __launch_bounds__(256) void attn1_combine_kernel(
    const float* __restrict__ part, bf16* __restrict__ attnT) {
  int bh = blockIdx.x, t = threadIdx.x;
  int g = t >> 2, kd0 = (t & 3) * 8;
  const float* base = part + (size_t)bh * 16 * PSTRIDE_;
  float gm = -1e30f, L = 0.f;
  float o[8];
#pragma unroll
  for (int j = 0; j < 8; j++) o[j] = 0.f;
  for (int tl = 0; tl < 16; tl++) {
    const float* pt = base + tl * PSTRIDE_;
    float m = pt[g], l = pt[64 + g];
    float nm = fmaxf(gm, m);
    float a0 = __expf(gm - nm), a1 = __expf(m - nm);
    L = L * a0 + l * a1;
    float4 x0 = *(const float4*)(pt + 128 + g * 32 + kd0);
    float4 x1 = *(const float4*)(pt + 128 + g * 32 + kd0 + 4);
    o[0] = o[0] * a0 + x0.x * a1; o[1] = o[1] * a0 + x0.y * a1;
    o[2] = o[2] * a0 + x0.z * a1; o[3] = o[3] * a0 + x0.w * a1;
    o[4] = o[4] * a0 + x1.x * a1; o[5] = o[5] * a0 + x1.y * a1;
    o[6] = o[6] * a0 + x1.z * a1; o[7] = o[7] * a0 + x1.w * a1;
    gm = nm;
  }
  float inv = 1.0f / L;
  bf16* dst = attnT + (size_t)bh * (KD_ * AG_);
#pragma unroll
  for (int j = 0; j < 8; j++)
    dst[(kd0 + j) * AG_ + g] = (bf16)(o[j] * inv);
}

// ------------------------------ K4: stage 2 --------------------------------
__global__ __launch_bounds__(256) void attn2_kernel(
    const bf16* __restrict__ qT, const bf16* __restrict__ aT,
    const bf16* __restrict__ attnT, const bf16* __restrict__ ab,
    bf16* __restrict__ outa) {
  __shared__ __align__(16) bf16 Ps[4][64][72];
  int nt = blockIdx.x * 256;
  int bh = blockIdx.y, b = bh >> 3, nh = bh & 7;
  int t = threadIdx.x, wave = t >> 6, lane = t & 63, quad = lane >> 4, l16 = lane & 15;
  const bf16* qb = qT + (size_t)bh * N_ * KD_;
  const bf16* aTb = aT + (size_t)bh * (AG_ * KD_);
  const bf16* atb = attnT + (size_t)bh * (KD_ * AG_);
  bf16x8 afr[4], tfr[2][2];
#pragma unroll
  for (int gi = 0; gi < 4; gi++)
    afr[gi] = *(const bf16x8*)(aTb + (gi * 16 + l16) * KD_ + quad * 8);
#pragma unroll
  for (int ci = 0; ci < 2; ci++)
#pragma unroll
    for (int ks = 0; ks < 2; ks++)
      tfr[ci][ks] = *(const bf16x8*)(atb + (ci * 16 + l16) * AG_ + ks * 32 + quad * 8);
  const bf16* abh = ab + (size_t)nh * N_ * AG_;
  int nloc = wave * 64;
  f32x4 zero4 = (f32x4){0.f, 0.f, 0.f, 0.f};
#pragma unroll
  for (int mi = 0; mi < 4; mi++) {
    bf16x8 qf = *(const bf16x8*)(qb + (size_t)(nt + nloc + mi * 16 + l16) * KD_ + quad * 8);
    f32x4 s[4];
#pragma unroll
    for (int gi = 0; gi < 4; gi++)
      s[gi] = MFMA16(qf, afr[gi], zero4);
    int n0 = nt + nloc + mi * 16 + quad * 4;
#pragma unroll
    for (int gi = 0; gi < 4; gi++) {
      int g = gi * 16 + l16;
#pragma unroll
      for (int r = 0; r < 4; r++)
        s[gi][r] = s[gi][r] * SCALE_ + (float)abh[(size_t)(n0 + r) * AG_ + g];
    }
#pragma unroll
    for (int r = 0; r < 4; r++) {
      float mx = fmaxf(fmaxf(s[0][r], s[1][r]), fmaxf(s[2][r], s[3][r]));
#pragma unroll
      for (int off = 1; off < 16; off <<= 1) mx = fmaxf(mx, __shfl_xor(mx, off));
      float rs = 0.f;
#pragma unroll
      for (int gi = 0; gi < 4; gi++) {
        float p = __expf(s[gi][r] - mx);
        s[gi][r] = p; rs += p;
      }
#pragma unroll
      for (int off = 1; off < 16; off <<= 1) rs += __shfl_xor(rs, off);
      float inv = 1.0f / rs;
#pragma unroll
      for (int gi = 0; gi < 4; gi++) s[gi][r] *= inv;
    }
#pragma unroll
    for (int gi = 0; gi < 4; gi++)
#pragma unroll
      for (int r = 0; r < 4; r++)
        Ps[wave][mi * 16 + quad * 4 + r][gi * 16 + l16] = (bf16)s[gi][r];
  }
  __syncthreads();
  f32x4 O[4][2];
#pragma unroll
  for (int mi = 0; mi < 4; mi++) { O[mi][0] = zero4; O[mi][1] = zero4; }
#pragma unroll
  for (int ks = 0; ks < 2; ks++) {
    bf16x8 pf[4];
#pragma unroll
    for (int mi = 0; mi < 4; mi++)
      pf[mi] = *(const bf16x8*)&Ps[wave][mi * 16 + l16][ks * 32 + quad * 8];
#pragma unroll
    for (int mi = 0; mi < 4; mi++)
#pragma unroll
      for (int ci = 0; ci < 2; ci++)
        O[mi][ci] = MFMA16(pf[mi], tfr[ci][ks], O[mi][ci]);
  }
  bf16* ob = outa + (size_t)b * C_ * N_;
#pragma unroll
  for (int mi = 0; mi < 4; mi++) {
    int n0 = nt + nloc + mi * 16 + quad * 4;
#pragma unroll
    for (int ci = 0; ci < 2; ci++) {
      int c = nh * KD_ + ci * 16 + l16;
      union { ushort4 u; bf16 e[4]; } pk;
#pragma unroll
      for (int r = 0; r < 4; r++) pk.e[r] = (bf16)O[mi][ci][r];
      *(ushort4*)(ob + (size_t)c * N_ + n0) = pk.u;
    }
  }
}

// -------------- K5: fused pe dwconv + add + transpose ----------------------
// houT[b][n][c] = outa[b][c][n] + BN(dwconv3x3(vv))[c][n]
// One block per (b, h-row, 64-c tile). Unit = (c_local, w-octet); lanes = c
// so the houT stores are 128B coalesced. No LDS.
__global__ __launch_bounds__(256) void pe_tr_kernel(
    const bf16* __restrict__ vv, const bf16* __restrict__ outa,
    const float* __restrict__ pw, const float* __restrict__ bn,
    bf16* __restrict__ hT) {
  int b = blockIdx.x, n0 = blockIdx.y * 64, c0 = blockIdx.z * 64;
  int h = n0 >> 6;
  int t = threadIdx.x;
#pragma unroll
  for (int half = 0; half < 2; half++) {
    int u = half * 256 + t;
    int cl = u & 63, oct = u >> 6;  // oct 0..3 (half 0), 4..7 (half 1)
    int w0 = oct * 8;
    int c = c0 + cl;
    const bf16* vrow = vv + ((size_t)b * C_ + c) * N_;
    float r[3][10];
#pragma unroll
    for (int dy = 0; dy < 3; dy++) {
      int hh = h + dy - 1;
      if ((unsigned)hh < 64u) {
        union { uint4 q; bf16 e[8]; } pk;
        pk.q = *(const uint4*)(vrow + hh * 64 + w0);
#pragma unroll
        for (int j = 0; j < 8; j++) r[dy][j + 1] = (float)pk.e[j];
        r[dy][0] = (w0 > 0) ? (float)vrow[hh * 64 + w0 - 1] : 0.f;
        r[dy][9] = (w0 < 56) ? (float)vrow[hh * 64 + w0 + 8] : 0.f;
      } else {
#pragma unroll
        for (int j = 0; j < 10; j++) r[dy][j] = 0.f;
      }
    }
    const float* wc = pw + c * 9;
    float w00 = wc[0], w01 = wc[1], w02 = wc[2];
    float w10 = wc[3], w11 = wc[4], w12 = wc[5];
    float w20 = wc[6], w21 = wc[7], w22 = wc[8];
    float sc = bn[c] * rsqrtf(bn[3 * C_ + c] + 1e-5f);
    float sh = bn[C_ + c] - bn[2 * C_ + c] * sc;
    union { uint4 q; bf16 e[8]; } po;
    po.q = *(const uint4*)(outa + ((size_t)b * C_ + c) * N_ + n0 + w0);
    bf16* dst = hT + ((size_t)b * N_ + n0 + w0) * C_ + c;
#pragma unroll
    for (int j = 0; j < 8; j++) {
      float a = r[0][j] * w00 + r[0][j + 1] * w01 + r[0][j + 2] * w02 +
                r[1][j] * w10 + r[1][j + 1] * w11 + r[1][j + 2] * w12 +
                r[2][j] * w20 + r[2][j + 1] * w21 + r[2][j + 2] * w22;
      dst[(size_t)j * C_] = (bf16)((float)po.e[j] + a * sc + sh);
    }
  }
}

// ------------------------------ K6: proj GEMM -------------------------------
// A = wpb [256][256] bf16 (BN-folded), B = houT [b][n][256] bf16.
__global__ __launch_bounds__(256) void proj_gemm_kernel(
    const bf16* __restrict__ hT, const bf16* __restrict__ wpb,
    const float* __restrict__ shp, float* __restrict__ out) {
  int nt = blockIdx.x * 128, ot = blockIdx.y * 128, b = blockIdx.z;
  __shared__ __align__(16) bf16 As[128][32];
  __shared__ __align__(16) bf16 Bs[128][32];
  int t = threadIdx.x, wave = t >> 6, lane = t & 63, quad = lane >> 4, l16 = lane & 15;
  int wm = (wave >> 1) * 64, wn = (wave & 1) * 64;
  int lr = lane >> 2, lc = (lane & 3) * 8;
  f32x4 acc[4][4];
#pragma unroll
  for (int mi = 0; mi < 4; mi++)
#pragma unroll
    for (int ni = 0; ni < 4; ni++) acc[mi][ni] = (f32x4){0.f, 0.f, 0.f, 0.f};
  const bf16* hTb = hT + (size_t)b * N_ * C_;
  for (int k0 = 0; k0 < 256; k0 += 32) {
    __syncthreads();
#pragma unroll
    for (int i = 0; i < 2; i++) {
      int r0 = wave * 32 + i * 16;
      gll16(wpb + (size_t)(ot + r0 + lr) * C_ + k0 + lc, &As[r0][0]);
      gll16(hTb + (size_t)(nt + r0 + lr) * C_ + k0 + lc, &Bs[r0][0]);
    }
    __syncthreads();
    bf16x8 af[4], bfv[4];
#pragma unroll
    for (int mi = 0; mi < 4; mi++)
      af[mi] = *(const bf16x8*)&As[wm + mi * 16 + l16][quad * 8];
#pragma unroll
    for (int ni = 0; ni < 4; ni++)
      bfv[ni] = *(const bf16x8*)&Bs[wn + ni * 16 + l16][quad * 8];
#pragma unroll
    for (int mi = 0; mi < 4; mi++)
#pragma unroll
      for (int ni = 0; ni < 4; ni++)
        acc[mi][ni] = MFMA16(af[mi], bfv[ni], acc[mi][ni]);
  }
  float* ob = out + (size_t)b * C_ * N_;
#pragma unroll
  for (int mi = 0; mi < 4; mi++) {
    int o0 = ot + wm + mi * 16 + quad * 4;
    float4 s4 = *(const float4*)(shp + o0);
    float sh[4] = {s4.x, s4.y, s4.z, s4.w};
#pragma unroll
    for (int ni = 0; ni < 4; ni++) {
      int n = nt + wn + ni * 16 + l16;
#pragma unroll
      for (int r = 0; r < 4; r++)
        ob[(size_t)(o0 + r) * N_ + n] = acc[mi][ni][r] + sh[r];
    }
  }
}

// ------------------------------ launcher -----------------------------------
extern "C" void kernel_launch(void* const* d_in, const int* in_sizes, int n_in,
                              void* d_out, int out_size, void* d_ws, size_t ws_size,
                              hipStream_t stream) {
  const float* x = (const float*)d_in[0];
  const float* qkv_w = (const float*)d_in[1];
  const float* qkv_bn = (const float*)d_in[2];
  const float* pe_w = (const float*)d_in[3];
  const float* pe_bn = (const float*)d_in[4];
  const float* proj_w = (const float*)d_in[5];
  const float* proj_bn = (const float*)d_in[6];
  const float* an_bias = (const float*)d_in[7];
  const float* na_bias = (const float*)d_in[8];
  const float* ah_bias = (const float*)d_in[9];
  const float* aw_bias = (const float*)d_in[10];
  const float* ha_bias = (const float*)d_in[11];
  const float* wa_bias = (const float*)d_in[12];

  char* ws = (char*)d_ws;
  bf16* qT = (bf16*)(ws + 0);                 //  33,554,432
  bf16* kT = (bf16*)(ws + 33554432);          //  33,554,432 (later houT)
  bf16* vv = (bf16*)(ws + 67108864);          //  33,554,432
  bf16* pb = (bf16*)(ws + 100663296);         //   4,194,304
  bf16* ab = (bf16*)(ws + 104857600);         //   4,194,304
  bf16* aT = (bf16*)(ws + 109051904);         //     524,288
  bf16* attnT = (bf16*)(ws + 109576192);      //     524,288
  bf16* outa = (bf16*)(ws + 110100480);       //  33,554,432 (earlier xT + part)
  bf16* wqb = (bf16*)(ws + 143654912);        //     393,216
  bf16* wpb = (bf16*)(ws + 144048128);        //     131,072
  float* shq = (float*)(ws + 144179200);      //       4,096
  float* shp = (float*)(ws + 144183296);      //       4,096 -> 144,187,392
  bf16* xT = outa;                             // alias: dead before attn1
  bf16* houT = kT;                             // alias: kT dead after attn1
  float* part = (float*)outa;                  // partials, dead before attn2

  prep_w_kernel<<<1024, 256, 0, stream>>>(qkv_w, qkv_bn, proj_w, proj_bn,
                                          wqb, shq, wpb, shp);
  bias_pb_kernel<<<8192, 256, 0, stream>>>(an_bias, ah_bias, aw_bias, pb);
  bias_ab_kernel<<<8192, 256, 0, stream>>>(na_bias, ha_bias, wa_bias, ab);
  transpose_x_kernel<<<dim3(16, 64, 4), 256, 0, stream>>>(x, xT);
  qkv_gemm_kernel<<<dim3(32, 6, 16), 256, 0, stream>>>(xT, wqb, shq, qT, kT, vv);
  pool_kernel<<<1024, 256, 0, stream>>>(qT, aT);
  attn1_kernel<<<dim3(16, 128), 256, 0, stream>>>(kT, vv, aT, pb, part);
  attn1_combine_kernel<<<128, 256, 0, stream>>>(part, attnT);
  attn2_kernel<<<dim3(16, 128), 256, 0, stream>>>(qT, aT, attnT, ab, outa);
  pe_tr_kernel<<<dim3(16, 64, 4), 256, 0, stream>>>(vv, outa, pe_w, pe_bn, houT);
  proj_gemm_kernel<<<dim3(32, 2, 16), 256, 0, stream>>>(houT, wpb, shp,
                                                        (float*)d_out);
}